// Round 1
// baseline (1490.509 us; speedup 1.0000x reference)
//
#include <hip/hip_runtime.h>
#include <hip/hip_bf16.h>
#include <stdint.h>

#define B_ 4
#define F_ 1024
#define S_ 2048
#define K_ 7
#define SP_ (S_ + K_ - 1)   // 2054 padded rows (6 zero rows at the front)

using f32x4 = __attribute__((ext_vector_type(4))) float;
using s16x8 = __attribute__((ext_vector_type(8))) short;
using bf16 = __hip_bfloat16;

// -------- async global->LDS 16B (wave-uniform base + lane*16 semantics) -----
typedef const __attribute__((address_space(1))) void gvoid_t;
typedef __attribute__((address_space(3))) void lvoid_t;
__device__ __forceinline__ void async16(const void* g, void* l) {
    __builtin_amdgcn_global_load_lds((gvoid_t*)g, (lvoid_t*)l, 16, 0, 0);
}

__device__ __forceinline__ void store_out(float* p, float v) { *p = v; }
__device__ __forceinline__ void store_out(bf16* p, float v) { *p = __float2bfloat16(v); }

// ---------------------------------------------------------------------------
// zero the 6 halo rows of both transposed buffers
__global__ void zero_pads(bf16* xT, bf16* hT) {
    int i = blockIdx.x * 256 + threadIdx.x;
    const int n = B_ * (K_ - 1) * F_;   // 24576 per buffer
    if (i < n) {
        int b = i / ((K_ - 1) * F_);
        int r = i % ((K_ - 1) * F_);
        bf16 z = __float2bfloat16(0.0f);
        xT[(size_t)b * SP_ * F_ + r] = z;
        hT[(size_t)b * SP_ * F_ + r] = z;
    }
}

// out = inp + pos_embd, transposed to xT[b][6+s][f] as bf16 (64x64 LDS tiles)
__global__ void prep_x(const float* __restrict__ inp, const float* __restrict__ pos,
                       bf16* __restrict__ xT) {
    __shared__ bf16 tile[64][66];
    int b = blockIdx.z;
    int f0 = blockIdx.y * 64, s0 = blockIdx.x * 64;
    int tj = threadIdx.x & 63;     // s within tile
    int t4 = threadIdx.x >> 6;     // 0..3
#pragma unroll
    for (int r = 0; r < 16; ++r) {
        int i = r * 4 + t4;        // f within tile
        size_t off = (size_t)(f0 + i) * S_ + s0 + tj;
        float v = inp[(size_t)b * F_ * S_ + off] + pos[off];
        tile[i][tj] = __float2bfloat16(v);
    }
    __syncthreads();
#pragma unroll
    for (int r = 0; r < 16; ++r) {
        int j = r * 4 + t4;        // s within tile
        xT[(size_t)b * SP_ * F_ + (size_t)(6 + s0 + j) * F_ + f0 + tj] = tile[tj][j];
    }
}

// weights [co][ci][t] fp32  ->  Wb[t][co][ci] bf16
__global__ void wconv(const float* __restrict__ w, bf16* __restrict__ wt) {
    int i = blockIdx.x * 256 + threadIdx.x;   // co*F + ci
    if (i >= F_ * F_) return;
    const float* src = w + (size_t)i * K_;
#pragma unroll
    for (int t = 0; t < K_; ++t)
        wt[(size_t)t * F_ * F_ + i] = __float2bfloat16(src[t]);
}

// causal conv as 7-tap GEMM. Wb:[7][F][F] (A, [M][K]); xT:[B][SP][F] (B^T, [N][K])
// out:[B][F][S].  128x128 tile, BK=64, 4 waves (2x2), 16x16x32 bf16 MFMA.
template <typename OutT>
__global__ void conv_gemm(const bf16* __restrict__ W7, const bf16* __restrict__ xT,
                          OutT* __restrict__ out) {
    __shared__ bf16 tA[128][64];
    __shared__ bf16 tB[128][64];
    int b  = blockIdx.z;
    int m0 = blockIdx.y * 128;   // co
    int n0 = blockIdx.x * 128;   // s
    int tid = threadIdx.x;
    int lane = tid & 63, wid = tid >> 6;
    int wm = wid >> 1, wn = wid & 1;          // 2x2 waves -> 64x64 each

    f32x4 acc[4][4] = {};

    const size_t xbase = (size_t)b * SP_ * F_;
    int srow = tid >> 3;        // 0..31 staging row group
    int cpart = tid & 7;        // 16B chunk within a 64-elem row

    for (int t = 0; t < K_; ++t) {
        const bf16* Wt = W7 + (size_t)t * F_ * F_ + (size_t)m0 * F_;
        const bf16* Xt = xT + xbase + (size_t)(n0 + t) * F_;
        for (int kb = 0; kb < F_ / 64; ++kb) {
            const bf16* wa = Wt + kb * 64 + cpart * 8;
            const bf16* xa = Xt + kb * 64 + cpart * 8;
#pragma unroll
            for (int j = 0; j < 4; ++j) {
                int r = j * 32 + srow;
                async16(wa + (size_t)r * F_, &tA[r][cpart * 8]);
            }
#pragma unroll
            for (int j = 0; j < 4; ++j) {
                int r = j * 32 + srow;
                async16(xa + (size_t)r * F_, &tB[r][cpart * 8]);
            }
            __syncthreads();   // drains vmcnt+lgkmcnt per gfx950 semantics
#pragma unroll
            for (int kk = 0; kk < 2; ++kk) {
                int krow = kk * 32 + (lane >> 4) * 8;
                s16x8 af[4], bfr[4];
#pragma unroll
                for (int m = 0; m < 4; ++m)
                    af[m] = *(const s16x8*)&tA[wm * 64 + m * 16 + (lane & 15)][krow];
#pragma unroll
                for (int n = 0; n < 4; ++n)
                    bfr[n] = *(const s16x8*)&tB[wn * 64 + n * 16 + (lane & 15)][krow];
#pragma unroll
                for (int m = 0; m < 4; ++m)
#pragma unroll
                    for (int n = 0; n < 4; ++n)
                        acc[m][n] = __builtin_amdgcn_mfma_f32_16x16x32_bf16(
                            af[m], bfr[n], acc[m][n], 0, 0, 0);
            }
            __syncthreads();
        }
    }

    // epilogue: C/D layout col=lane&15, row=(lane>>4)*4+reg   [m89-verified]
    int cm = (lane >> 4) * 4;
    int cn = lane & 15;
    size_t obase = (size_t)b * F_ * S_;
#pragma unroll
    for (int m = 0; m < 4; ++m)
#pragma unroll
        for (int n = 0; n < 4; ++n)
#pragma unroll
            for (int r = 0; r < 4; ++r) {
                int rr = m0 + wm * 64 + m * 16 + cm + r;
                int cc = n0 + wn * 64 + n * 16 + cn;
                store_out(out + obase + (size_t)rr * S_ + cc, acc[m][n][r]);
            }
}

// per-(b,f) row stats of relu(x) over S: mean and 1/denom
__global__ void rowstats(const float* __restrict__ x, float2* __restrict__ stats) {
    int row = blockIdx.x * 4 + (threadIdx.x >> 6);   // 4096 rows
    int lane = threadIdx.x & 63;
    const float* p = x + (size_t)row * S_;
    float s1 = 0.f, s2 = 0.f;
#pragma unroll
    for (int j = 0; j < S_; j += 256) {
        float4 v = *(const float4*)(p + j + lane * 4);
        float a = fmaxf(v.x, 0.f), b = fmaxf(v.y, 0.f);
        float c = fmaxf(v.z, 0.f), d = fmaxf(v.w, 0.f);
        s1 += a + b + c + d;
        s2 += a * a + b * b + c * c + d * d;
    }
#pragma unroll
    for (int d = 32; d; d >>= 1) { s1 += __shfl_xor(s1, d); s2 += __shfl_xor(s2, d); }
    if (lane == 0) {
        float m = s1 / (float)S_;
        float ss = s2 - (float)S_ * m * m;
        ss = fmaxf(ss, 0.f);
        float denom = (sqrtf(ss) + 1e-5f) * (1.0f / sqrtf((float)S_));
        stats[row] = make_float2(m, 1.0f / denom);
    }
}

// h = (relu(x)-m)*inv, transposed to hT[b][6+s][f] bf16
__global__ void normT(const float* __restrict__ x, const float2* __restrict__ stats,
                      bf16* __restrict__ hT) {
    __shared__ bf16 tile[64][66];
    int b = blockIdx.z;
    int f0 = blockIdx.y * 64, s0 = blockIdx.x * 64;
    int tj = threadIdx.x & 63;
    int t4 = threadIdx.x >> 6;
#pragma unroll
    for (int r = 0; r < 16; ++r) {
        int i = r * 4 + t4;
        float2 st = stats[b * F_ + f0 + i];
        float v = x[(size_t)b * F_ * S_ + (size_t)(f0 + i) * S_ + s0 + tj];
        v = fmaxf(v, 0.f);
        tile[i][tj] = __float2bfloat16((v - st.x) * st.y);
    }
    __syncthreads();
#pragma unroll
    for (int r = 0; r < 16; ++r) {
        int j = r * 4 + t4;
        hT[(size_t)b * SP_ * F_ + (size_t)(6 + s0 + j) * F_ + f0 + tj] = tile[tj][j];
    }
}

// y = inp*(cumsum_f(depth)/divisor + point) + shift   (cumsum over f, inclusive)
__global__ void combine(const float* __restrict__ inp, const float* __restrict__ divisor,
                        const bf16* __restrict__ depth, const bf16* __restrict__ point,
                        const bf16* __restrict__ shiftb, float* __restrict__ y) {
    int idx = blockIdx.x * 256 + threadIdx.x;   // over B*S
    if (idx >= B_ * S_) return;
    int b = idx / S_, s = idx % S_;
    size_t base = (size_t)b * F_ * S_ + s;
    float acc = 0.f;
    for (int f = 0; f < F_; ++f) {
        size_t o = base + (size_t)f * S_;
        acc += __bfloat162float(depth[o]);
        float yv = inp[o] * (acc / divisor[f] + __bfloat162float(point[o]))
                 + __bfloat162float(shiftb[o]);
        y[o] = yv;
    }
}

__global__ void finalnorm(const float* __restrict__ y, const float2* __restrict__ stats,
                          float* __restrict__ out) {
    size_t i = (size_t)blockIdx.x * 256 + threadIdx.x;
    if (i >= (size_t)B_ * F_ * S_) return;
    float2 st = stats[i / S_];
    float v = fmaxf(y[i], 0.f);
    out[i] = (v - st.x) * st.y;
}

// ---------------------------------------------------------------------------
extern "C" void kernel_launch(void* const* d_in, const int* in_sizes, int n_in,
                              void* d_out, int out_size, void* d_ws, size_t ws_size,
                              hipStream_t stream) {
    const float* inp = (const float*)d_in[0];
    const float* pos = (const float*)d_in[1];
    const float* divisor = (const float*)d_in[2];
    const float* w[6] = { (const float*)d_in[3], (const float*)d_in[4],
                          (const float*)d_in[5], (const float*)d_in[6],
                          (const float*)d_in[7], (const float*)d_in[8] };
    float* out = (float*)d_out;

    size_t off = 0;
    auto alloc = [&](size_t bytes) {
        off = (off + 255) & ~(size_t)255;
        void* r = (char*)d_ws + off;
        off += bytes;
        return r;
    };
    bf16* xT  = (bf16*)alloc((size_t)B_ * SP_ * F_ * 2);
    bf16* hT  = (bf16*)alloc((size_t)B_ * SP_ * F_ * 2);
    bf16* Wb  = (bf16*)alloc((size_t)K_ * F_ * F_ * 2);
    float* O1 = (float*)alloc((size_t)B_ * F_ * S_ * 4);
    bf16* br[3];
    for (int i = 0; i < 3; ++i) br[i] = (bf16*)alloc((size_t)B_ * F_ * S_ * 2);
    float2* stats = (float2*)alloc((size_t)B_ * F_ * 8);
    float* ybuf = O1;  // O1 dead by combine time

    zero_pads<<<96, 256, 0, stream>>>(xT, hT);
    prep_x<<<dim3(S_ / 64, F_ / 64, B_), 256, 0, stream>>>(inp, pos, xT);

    for (int i = 0; i < 3; ++i) {
        wconv<<<F_ * F_ / 256, 256, 0, stream>>>(w[2 * i], Wb);
        conv_gemm<float><<<dim3(S_ / 128, F_ / 128, B_), 256, 0, stream>>>(Wb, xT, O1);
        rowstats<<<B_ * F_ / 4, 256, 0, stream>>>(O1, stats);
        normT<<<dim3(S_ / 64, F_ / 64, B_), 256, 0, stream>>>(O1, stats, hT);
        wconv<<<F_ * F_ / 256, 256, 0, stream>>>(w[2 * i + 1], Wb);
        conv_gemm<bf16><<<dim3(S_ / 128, F_ / 128, B_), 256, 0, stream>>>(Wb, hT, br[i]);
    }

    combine<<<B_ * S_ / 256, 256, 0, stream>>>(inp, divisor, br[0], br[1], br[2], ybuf);
    rowstats<<<B_ * F_ / 4, 256, 0, stream>>>(ybuf, stats);
    finalnorm<<<(B_ * F_ * S_) / 256, 256, 0, stream>>>(ybuf, stats, out);
}

// Round 2
// 1151.991 us; speedup vs baseline: 1.2939x; 1.2939x over previous
//
#include <hip/hip_runtime.h>
#include <hip/hip_bf16.h>
#include <stdint.h>

#define B_ 4
#define F_ 1024
#define S_ 2048
#define K_ 7
#define SP_ (S_ + K_ - 1)   // 2054 padded rows (6 zero rows at the front)
#define FC_ 64              // cumsum chunk size
#define NC_ (F_ / FC_)      // 16 chunks

using f32x4 = __attribute__((ext_vector_type(4))) float;
using s16x8 = __attribute__((ext_vector_type(8))) short;
using bf16 = __hip_bfloat16;

// -------- async global->LDS 16B (wave-uniform base + lane*16 semantics) -----
typedef const __attribute__((address_space(1))) void gvoid_t;
typedef __attribute__((address_space(3))) void lvoid_t;
__device__ __forceinline__ void async16(const void* g, void* l) {
    __builtin_amdgcn_global_load_lds((gvoid_t*)g, (lvoid_t*)l, 16, 0, 0);
}

__device__ __forceinline__ void store_out(float* p, float v) { *p = v; }
__device__ __forceinline__ void store_out(bf16* p, float v) { *p = __float2bfloat16(v); }

// ---------------------------------------------------------------------------
// zero the 6 halo rows of both transposed buffers
__global__ void zero_pads(bf16* xT, bf16* hT) {
    int i = blockIdx.x * 256 + threadIdx.x;
    const int n = B_ * (K_ - 1) * F_;   // 24576 per buffer
    if (i < n) {
        int b = i / ((K_ - 1) * F_);
        int r = i % ((K_ - 1) * F_);
        bf16 z = __float2bfloat16(0.0f);
        xT[(size_t)b * SP_ * F_ + r] = z;
        hT[(size_t)b * SP_ * F_ + r] = z;
    }
}

// out = inp + pos_embd, transposed to xT[b][6+s][f] as bf16 (64x64 LDS tiles)
__global__ void prep_x(const float* __restrict__ inp, const float* __restrict__ pos,
                       bf16* __restrict__ xT) {
    __shared__ bf16 tile[64][66];
    int b = blockIdx.z;
    int f0 = blockIdx.y * 64, s0 = blockIdx.x * 64;
    int tj = threadIdx.x & 63;     // s within tile
    int t4 = threadIdx.x >> 6;     // 0..3
#pragma unroll
    for (int r = 0; r < 16; ++r) {
        int i = r * 4 + t4;        // f within tile
        size_t off = (size_t)(f0 + i) * S_ + s0 + tj;
        float v = inp[(size_t)b * F_ * S_ + off] + pos[off];
        tile[i][tj] = __float2bfloat16(v);
    }
    __syncthreads();
#pragma unroll
    for (int r = 0; r < 16; ++r) {
        int j = r * 4 + t4;        // s within tile
        xT[(size_t)b * SP_ * F_ + (size_t)(6 + s0 + j) * F_ + f0 + tj] = tile[tj][j];
    }
}

// weights [co][ci][t] fp32  ->  Wb[t][co][ci] bf16
__global__ void wconv(const float* __restrict__ w, bf16* __restrict__ wt) {
    int i = blockIdx.x * 256 + threadIdx.x;   // co*F + ci
    if (i >= F_ * F_) return;
    const float* src = w + (size_t)i * K_;
#pragma unroll
    for (int t = 0; t < K_; ++t)
        wt[(size_t)t * F_ * F_ + i] = __float2bfloat16(src[t]);
}

// causal conv as 7-tap GEMM. Wb:[7][F][F] (A, [M][K]); xT:[B][SP][F] (B^T, [N][K])
// out:[B][F][S].  128x128 tile, BK=64, 4 waves (2x2), 16x16x32 bf16 MFMA.
template <typename OutT>
__global__ void conv_gemm(const bf16* __restrict__ W7, const bf16* __restrict__ xT,
                          OutT* __restrict__ out) {
    __shared__ bf16 tA[128][64];
    __shared__ bf16 tB[128][64];
    int b  = blockIdx.z;
    int m0 = blockIdx.y * 128;   // co
    int n0 = blockIdx.x * 128;   // s
    int tid = threadIdx.x;
    int lane = tid & 63, wid = tid >> 6;
    int wm = wid >> 1, wn = wid & 1;          // 2x2 waves -> 64x64 each

    f32x4 acc[4][4] = {};

    const size_t xbase = (size_t)b * SP_ * F_;
    int srow = tid >> 3;        // 0..31 staging row group
    int cpart = tid & 7;        // 16B chunk within a 64-elem row

    for (int t = 0; t < K_; ++t) {
        const bf16* Wt = W7 + (size_t)t * F_ * F_ + (size_t)m0 * F_;
        const bf16* Xt = xT + xbase + (size_t)(n0 + t) * F_;
        for (int kb = 0; kb < F_ / 64; ++kb) {
            const bf16* wa = Wt + kb * 64 + cpart * 8;
            const bf16* xa = Xt + kb * 64 + cpart * 8;
#pragma unroll
            for (int j = 0; j < 4; ++j) {
                int r = j * 32 + srow;
                async16(wa + (size_t)r * F_, &tA[r][cpart * 8]);
            }
#pragma unroll
            for (int j = 0; j < 4; ++j) {
                int r = j * 32 + srow;
                async16(xa + (size_t)r * F_, &tB[r][cpart * 8]);
            }
            __syncthreads();   // drains vmcnt+lgkmcnt per gfx950 semantics
#pragma unroll
            for (int kk = 0; kk < 2; ++kk) {
                int krow = kk * 32 + (lane >> 4) * 8;
                s16x8 af[4], bfr[4];
#pragma unroll
                for (int m = 0; m < 4; ++m)
                    af[m] = *(const s16x8*)&tA[wm * 64 + m * 16 + (lane & 15)][krow];
#pragma unroll
                for (int n = 0; n < 4; ++n)
                    bfr[n] = *(const s16x8*)&tB[wn * 64 + n * 16 + (lane & 15)][krow];
#pragma unroll
                for (int m = 0; m < 4; ++m)
#pragma unroll
                    for (int n = 0; n < 4; ++n)
                        acc[m][n] = __builtin_amdgcn_mfma_f32_16x16x32_bf16(
                            af[m], bfr[n], acc[m][n], 0, 0, 0);
            }
            __syncthreads();
        }
    }

    // epilogue: C/D layout col=lane&15, row=(lane>>4)*4+reg   [m89-verified]
    int cm = (lane >> 4) * 4;
    int cn = lane & 15;
    size_t obase = (size_t)b * F_ * S_;
#pragma unroll
    for (int m = 0; m < 4; ++m)
#pragma unroll
        for (int n = 0; n < 4; ++n)
#pragma unroll
            for (int r = 0; r < 4; ++r) {
                int rr = m0 + wm * 64 + m * 16 + cm + r;
                int cc = n0 + wn * 64 + n * 16 + cn;
                store_out(out + obase + (size_t)rr * S_ + cc, acc[m][n][r]);
            }
}

// per-(b,f) row stats of relu(x) over S: mean and 1/denom
__global__ void rowstats(const float* __restrict__ x, float2* __restrict__ stats) {
    int row = blockIdx.x * 4 + (threadIdx.x >> 6);   // 4096 rows
    int lane = threadIdx.x & 63;
    const float* p = x + (size_t)row * S_;
    float s1 = 0.f, s2 = 0.f;
#pragma unroll
    for (int j = 0; j < S_; j += 256) {
        float4 v = *(const float4*)(p + j + lane * 4);
        float a = fmaxf(v.x, 0.f), b = fmaxf(v.y, 0.f);
        float c = fmaxf(v.z, 0.f), d = fmaxf(v.w, 0.f);
        s1 += a + b + c + d;
        s2 += a * a + b * b + c * c + d * d;
    }
#pragma unroll
    for (int d = 32; d; d >>= 1) { s1 += __shfl_xor(s1, d); s2 += __shfl_xor(s2, d); }
    if (lane == 0) {
        float m = s1 / (float)S_;
        float ss = s2 - (float)S_ * m * m;
        ss = fmaxf(ss, 0.f);
        float denom = (sqrtf(ss) + 1e-5f) * (1.0f / sqrtf((float)S_));
        stats[row] = make_float2(m, 1.0f / denom);
    }
}

// h = (relu(x)-m)*inv, transposed to hT[b][6+s][f] bf16
__global__ void normT(const float* __restrict__ x, const float2* __restrict__ stats,
                      bf16* __restrict__ hT) {
    __shared__ bf16 tile[64][66];
    int b = blockIdx.z;
    int f0 = blockIdx.y * 64, s0 = blockIdx.x * 64;
    int tj = threadIdx.x & 63;
    int t4 = threadIdx.x >> 6;
#pragma unroll
    for (int r = 0; r < 16; ++r) {
        int i = r * 4 + t4;
        float2 st = stats[b * F_ + f0 + i];
        float v = x[(size_t)b * F_ * S_ + (size_t)(f0 + i) * S_ + s0 + tj];
        v = fmaxf(v, 0.f);
        tile[i][tj] = __float2bfloat16((v - st.x) * st.y);
    }
    __syncthreads();
#pragma unroll
    for (int r = 0; r < 16; ++r) {
        int j = r * 4 + t4;
        hT[(size_t)b * SP_ * F_ + (size_t)(6 + s0 + j) * F_ + f0 + tj] = tile[tj][j];
    }
}

// ---- hierarchical cumsum over f + elementwise combine ----------------------
// phase 1: per-(b,s) sums of 64-f chunks of depth -> partials[b][NC][s]
__global__ void combine_partial(const bf16* __restrict__ depth,
                                float* __restrict__ partials) {
    int idx = blockIdx.x * 256 + threadIdx.x;   // over B*NC*S
    int s = idx & (S_ - 1);
    int t = idx / S_;
    int fc = t % NC_;
    int b = t / NC_;
    const bf16* p = depth + (size_t)b * F_ * S_ + (size_t)(fc * FC_) * S_ + s;
    float acc = 0.f;
#pragma unroll
    for (int f = 0; f < FC_; ++f) acc += __bfloat162float(p[(size_t)f * S_]);
    partials[idx] = acc;
}

// phase 2: exclusive prefix of chunk partials + serial 64-f cumsum + combine.
// fc is uniform per block (S_ % 256 == 0) -> no divergence on the prefix loop.
__global__ void combine_apply(const float* __restrict__ inp, const float* __restrict__ divisor,
                              const bf16* __restrict__ depth, const bf16* __restrict__ point,
                              const bf16* __restrict__ shiftb,
                              const float* __restrict__ partials, float* __restrict__ y) {
    int idx = blockIdx.x * 256 + threadIdx.x;   // over B*NC*S
    int s = idx & (S_ - 1);
    int t = idx / S_;
    int fc = t % NC_;
    int b = t / NC_;
    float acc = 0.f;
    const float* pp = partials + (size_t)b * NC_ * S_ + s;
    for (int c = 0; c < fc; ++c) acc += pp[(size_t)c * S_];
    size_t base = (size_t)b * F_ * S_ + (size_t)(fc * FC_) * S_ + s;
#pragma unroll 4
    for (int f = 0; f < FC_; ++f) {
        size_t o = base + (size_t)f * S_;
        acc += __bfloat162float(depth[o]);
        float yv = inp[o] * (acc / divisor[fc * FC_ + f] + __bfloat162float(point[o]))
                 + __bfloat162float(shiftb[o]);
        y[o] = yv;
    }
}

__global__ void finalnorm(const float* __restrict__ y, const float2* __restrict__ stats,
                          float* __restrict__ out) {
    size_t i = (size_t)blockIdx.x * 256 + threadIdx.x;
    if (i >= (size_t)B_ * F_ * S_) return;
    float2 st = stats[i / S_];
    float v = fmaxf(y[i], 0.f);
    out[i] = (v - st.x) * st.y;
}

// ---------------------------------------------------------------------------
extern "C" void kernel_launch(void* const* d_in, const int* in_sizes, int n_in,
                              void* d_out, int out_size, void* d_ws, size_t ws_size,
                              hipStream_t stream) {
    const float* inp = (const float*)d_in[0];
    const float* pos = (const float*)d_in[1];
    const float* divisor = (const float*)d_in[2];
    const float* w[6] = { (const float*)d_in[3], (const float*)d_in[4],
                          (const float*)d_in[5], (const float*)d_in[6],
                          (const float*)d_in[7], (const float*)d_in[8] };
    float* out = (float*)d_out;

    size_t off = 0;
    auto alloc = [&](size_t bytes) {
        off = (off + 255) & ~(size_t)255;
        void* r = (char*)d_ws + off;
        off += bytes;
        return r;
    };
    bf16* xT  = (bf16*)alloc((size_t)B_ * SP_ * F_ * 2);
    bf16* hT  = (bf16*)alloc((size_t)B_ * SP_ * F_ * 2);
    bf16* Wb  = (bf16*)alloc((size_t)K_ * F_ * F_ * 2);
    float* O1 = (float*)alloc((size_t)B_ * F_ * S_ * 4);
    bf16* br[3];
    for (int i = 0; i < 3; ++i) br[i] = (bf16*)alloc((size_t)B_ * F_ * S_ * 2);
    float2* stats = (float2*)alloc((size_t)B_ * F_ * 8);
    float* partials = (float*)alloc((size_t)B_ * NC_ * S_ * 4);
    float* ybuf = O1;  // O1 dead by combine time

    zero_pads<<<96, 256, 0, stream>>>(xT, hT);
    prep_x<<<dim3(S_ / 64, F_ / 64, B_), 256, 0, stream>>>(inp, pos, xT);

    for (int i = 0; i < 3; ++i) {
        wconv<<<F_ * F_ / 256, 256, 0, stream>>>(w[2 * i], Wb);
        conv_gemm<float><<<dim3(S_ / 128, F_ / 128, B_), 256, 0, stream>>>(Wb, xT, O1);
        rowstats<<<B_ * F_ / 4, 256, 0, stream>>>(O1, stats);
        normT<<<dim3(S_ / 64, F_ / 64, B_), 256, 0, stream>>>(O1, stats, hT);
        wconv<<<F_ * F_ / 256, 256, 0, stream>>>(w[2 * i + 1], Wb);
        conv_gemm<bf16><<<dim3(S_ / 128, F_ / 128, B_), 256, 0, stream>>>(Wb, hT, br[i]);
    }

    combine_partial<<<B_ * NC_ * S_ / 256, 256, 0, stream>>>(br[0], partials);
    combine_apply<<<B_ * NC_ * S_ / 256, 256, 0, stream>>>(inp, divisor, br[0], br[1], br[2],
                                                           partials, ybuf);
    rowstats<<<B_ * F_ / 4, 256, 0, stream>>>(ybuf, stats);
    finalnorm<<<(B_ * F_ * S_) / 256, 256, 0, stream>>>(ybuf, stats, out);
}

// Round 3
// 916.068 us; speedup vs baseline: 1.6271x; 1.2575x over previous
//
#include <hip/hip_runtime.h>
#include <hip/hip_bf16.h>
#include <stdint.h>

#define B_ 4
#define F_ 1024
#define S_ 2048
#define K_ 7
#define SP_ (S_ + K_ - 1)   // 2054 padded rows (6 zero rows at the front)
#define FC_ 64              // cumsum chunk size
#define NC_ (F_ / FC_)      // 16 chunks
#define FF_ ((size_t)F_ * F_)
#define BFS_ ((size_t)B_ * F_ * S_)
#define BSPF_ ((size_t)B_ * SP_ * F_)

using f32x4 = __attribute__((ext_vector_type(4))) float;
using s16x8 = __attribute__((ext_vector_type(8))) short;
using bf16 = __hip_bfloat16;

// -------- async global->LDS 16B (wave-uniform base + lane*16 semantics) -----
typedef const __attribute__((address_space(1))) void gvoid_t;
typedef __attribute__((address_space(3))) void lvoid_t;
__device__ __forceinline__ void async16(const void* g, void* l) {
    __builtin_amdgcn_global_load_lds((gvoid_t*)g, (lvoid_t*)l, 16, 0, 0);
}

__device__ __forceinline__ float bf2f(unsigned short u) {
    union { unsigned int i; float f; } c; c.i = ((unsigned int)u) << 16; return c.f;
}
__device__ __forceinline__ void store_out(float* p, float v) { *p = v; }
__device__ __forceinline__ void store_out(bf16* p, float v) { *p = __float2bfloat16(v); }

// ---------------------------------------------------------------------------
// zero the 6 halo rows of xT and nh branch buffers of hT
__global__ void zero_pads(bf16* xT, bf16* hT, int nh) {
    int i = blockIdx.x * 256 + threadIdx.x;
    const int per = B_ * (K_ - 1) * F_;   // 24576 per buffer
    int total = (1 + nh) * per;
    if (i >= total) return;
    int r = i / per, o = i % per;
    int b = o / ((K_ - 1) * F_);
    int rr = o % ((K_ - 1) * F_);
    bf16 z = __float2bfloat16(0.0f);
    if (r == 0) xT[(size_t)b * SP_ * F_ + rr] = z;
    else        hT[(size_t)(r - 1) * BSPF_ + (size_t)b * SP_ * F_ + rr] = z;
}

// out = inp + pos_embd, transposed to xT[b][6+s][f] as bf16 (64x64 LDS tiles)
__global__ void prep_x(const float* __restrict__ inp, const float* __restrict__ pos,
                       bf16* __restrict__ xT) {
    __shared__ bf16 tile[64][66];
    int b = blockIdx.z;
    int f0 = blockIdx.y * 64, s0 = blockIdx.x * 64;
    int tj = threadIdx.x & 63;     // s within tile
    int t4 = threadIdx.x >> 6;     // 0..3
#pragma unroll
    for (int r = 0; r < 16; ++r) {
        int i = r * 4 + t4;        // f within tile
        size_t off = (size_t)(f0 + i) * S_ + s0 + tj;
        float v = inp[(size_t)b * F_ * S_ + off] + pos[off];
        tile[i][tj] = __float2bfloat16(v);
    }
    __syncthreads();
#pragma unroll
    for (int r = 0; r < 16; ++r) {
        int j = r * 4 + t4;        // s within tile
        xT[(size_t)b * SP_ * F_ + (size_t)(6 + s0 + j) * F_ + f0 + tj] = tile[tj][j];
    }
}

// weights [co][ci][t] fp32  ->  Wb[t][co][ci] bf16
__global__ void wconv(const float* __restrict__ w, bf16* __restrict__ wt) {
    int i = blockIdx.x * 256 + threadIdx.x;   // co*F + ci
    if (i >= F_ * F_) return;
    const float* src = w + (size_t)i * K_;
#pragma unroll
    for (int t = 0; t < K_; ++t)
        wt[(size_t)t * FF_ + i] = __float2bfloat16(src[t]);
}

// causal conv as 7-tap GEMM, 3 branches batched via 1D grid + XCD swizzle.
// W:[branch][7][F][F] (A); X:[branch?][B][SP][F] (B^T rows); out:[branch][B][F][S]
// 128x128 tile, BK=64, 4 waves (2x2), 16x16x32 bf16 MFMA. grid.x = 16*8*nz.
template <typename OutT>
__global__ void conv_gemm(const bf16* __restrict__ Wbase, const bf16* __restrict__ Xbase,
                          OutT* __restrict__ Obase,
                          long wStride, long xStride, long oStride) {
    __shared__ bf16 tA[128][64];
    __shared__ bf16 tB[128][64];
    // bijective XCD swizzle (gridDim.x % 8 == 0)
    int wg = blockIdx.x;
    int cpx = gridDim.x >> 3;
    int swz = (wg & 7) * cpx + (wg >> 3);
    int sx = swz & 15;          // n-tile (S/128 = 16)
    int t1 = swz >> 4;
    int sy = t1 & 7;            // m-tile (F/128 = 8)
    int sz = t1 >> 3;           // b + 4*branch
    int j = sz >> 2, b = sz & 3;

    const bf16* Wbr = Wbase + (size_t)j * wStride;
    const bf16* Xbr = Xbase + (size_t)j * xStride + (size_t)b * SP_ * F_;
    OutT* out = Obase + (size_t)j * oStride + (size_t)b * F_ * S_;
    int m0 = sy * 128, n0 = sx * 128;

    int tid = threadIdx.x;
    int lane = tid & 63, wid = tid >> 6;
    int wm = wid >> 1, wn = wid & 1;          // 2x2 waves -> 64x64 each

    f32x4 acc[4][4] = {};
    int srow = tid >> 3;        // 0..31 staging row group
    int cpart = tid & 7;        // 16B chunk within a 64-elem row

    for (int t = 0; t < K_; ++t) {
        const bf16* Wt = Wbr + (size_t)t * FF_ + (size_t)m0 * F_;
        const bf16* Xt = Xbr + (size_t)(n0 + t) * F_;
        for (int kb = 0; kb < F_ / 64; ++kb) {
            const bf16* wa = Wt + kb * 64 + cpart * 8;
            const bf16* xa = Xt + kb * 64 + cpart * 8;
#pragma unroll
            for (int q = 0; q < 4; ++q) {
                int r = q * 32 + srow;
                async16(wa + (size_t)r * F_, &tA[r][cpart * 8]);
            }
#pragma unroll
            for (int q = 0; q < 4; ++q) {
                int r = q * 32 + srow;
                async16(xa + (size_t)r * F_, &tB[r][cpart * 8]);
            }
            __syncthreads();   // drains vmcnt+lgkmcnt per gfx950 semantics
#pragma unroll
            for (int kk = 0; kk < 2; ++kk) {
                int krow = kk * 32 + (lane >> 4) * 8;
                s16x8 af[4], bfr[4];
#pragma unroll
                for (int m = 0; m < 4; ++m)
                    af[m] = *(const s16x8*)&tA[wm * 64 + m * 16 + (lane & 15)][krow];
#pragma unroll
                for (int n = 0; n < 4; ++n)
                    bfr[n] = *(const s16x8*)&tB[wn * 64 + n * 16 + (lane & 15)][krow];
#pragma unroll
                for (int m = 0; m < 4; ++m)
#pragma unroll
                    for (int n = 0; n < 4; ++n)
                        acc[m][n] = __builtin_amdgcn_mfma_f32_16x16x32_bf16(
                            af[m], bfr[n], acc[m][n], 0, 0, 0);
            }
            __syncthreads();
        }
    }

    // epilogue: C/D layout col=lane&15, row=(lane>>4)*4+reg   [m89-verified]
    int cm = (lane >> 4) * 4;
    int cn = lane & 15;
#pragma unroll
    for (int m = 0; m < 4; ++m)
#pragma unroll
        for (int n = 0; n < 4; ++n)
#pragma unroll
            for (int r = 0; r < 4; ++r) {
                int rr = m0 + wm * 64 + m * 16 + cm + r;
                int cc = n0 + wn * 64 + n * 16 + cn;
                store_out(out + (size_t)rr * S_ + cc, acc[m][n][r]);
            }
}

// per-row stats of relu(x) over S: mean and 1/denom  (bf16 input, vectorized)
__global__ void rowstats_bf16(const bf16* __restrict__ x, float2* __restrict__ stats) {
    int row = blockIdx.x * 4 + (threadIdx.x >> 6);
    int lane = threadIdx.x & 63;
    const bf16* p = x + (size_t)row * S_;
    float s1 = 0.f, s2 = 0.f;
#pragma unroll
    for (int q = 0; q < S_ / 512; ++q) {
        s16x8 v = *(const s16x8*)(p + q * 512 + lane * 8);
#pragma unroll
        for (int e = 0; e < 8; ++e) {
            float f = fmaxf(bf2f((unsigned short)v[e]), 0.f);
            s1 += f; s2 += f * f;
        }
    }
#pragma unroll
    for (int d = 32; d; d >>= 1) { s1 += __shfl_xor(s1, d); s2 += __shfl_xor(s2, d); }
    if (lane == 0) {
        float m = s1 / (float)S_;
        float ss = fmaxf(s2 - (float)S_ * m * m, 0.f);
        float denom = (sqrtf(ss) + 1e-5f) * (1.0f / sqrtf((float)S_));
        stats[row] = make_float2(m, 1.0f / denom);
    }
}

// fp32-input variant (for y before finalnorm)
__global__ void rowstats_f32(const float* __restrict__ x, float2* __restrict__ stats) {
    int row = blockIdx.x * 4 + (threadIdx.x >> 6);
    int lane = threadIdx.x & 63;
    const float* p = x + (size_t)row * S_;
    float s1 = 0.f, s2 = 0.f;
#pragma unroll
    for (int q = 0; q < S_; q += 256) {
        float4 v = *(const float4*)(p + q + lane * 4);
        float a = fmaxf(v.x, 0.f), bb = fmaxf(v.y, 0.f);
        float c = fmaxf(v.z, 0.f), d = fmaxf(v.w, 0.f);
        s1 += a + bb + c + d;
        s2 += a * a + bb * bb + c * c + d * d;
    }
#pragma unroll
    for (int d = 32; d; d >>= 1) { s1 += __shfl_xor(s1, d); s2 += __shfl_xor(s2, d); }
    if (lane == 0) {
        float m = s1 / (float)S_;
        float ss = fmaxf(s2 - (float)S_ * m * m, 0.f);
        float denom = (sqrtf(ss) + 1e-5f) * (1.0f / sqrtf((float)S_));
        stats[row] = make_float2(m, 1.0f / denom);
    }
}

// h = (relu(x)-m)*inv, transposed to hT[z][6+s][f] bf16. grid.z = nz (rows of [z][F][S])
__global__ void normT(const bf16* __restrict__ x, const float2* __restrict__ stats,
                      bf16* __restrict__ hT) {
    __shared__ bf16 tile[64][72];
    int z = blockIdx.z;
    int f0 = blockIdx.y * 64, s0 = blockIdx.x * 64;
    const bf16* xb = x + (size_t)z * F_ * S_;
    bf16* hb = hT + (size_t)z * SP_ * F_;
    const float2* st = stats + (size_t)z * F_;
    int i = threadIdx.x >> 3;      // 0..31
    int c8 = threadIdx.x & 7;
#pragma unroll
    for (int p = 0; p < 2; ++p) {
        int r = i + p * 32;
        float2 s = st[f0 + r];
        s16x8 v = *(const s16x8*)(xb + (size_t)(f0 + r) * S_ + s0 + c8 * 8);
#pragma unroll
        for (int e = 0; e < 8; ++e) {
            float f = fmaxf(bf2f((unsigned short)v[e]), 0.f);
            tile[r][c8 * 8 + e] = __float2bfloat16((f - s.x) * s.y);
        }
    }
    __syncthreads();
    int tj = threadIdx.x & 63;     // f within tile
    int t4 = threadIdx.x >> 6;
#pragma unroll
    for (int r = 0; r < 16; ++r) {
        int jrow = r * 4 + t4;
        hb[(size_t)(6 + s0 + jrow) * F_ + f0 + tj] = tile[tj][jrow];
    }
}

// ---- hierarchical cumsum over f + elementwise combine ----------------------
__global__ void combine_partial(const bf16* __restrict__ depth,
                                float* __restrict__ partials) {
    int idx = blockIdx.x * 256 + threadIdx.x;   // over B*NC*S
    int s = idx & (S_ - 1);
    int t = idx / S_;
    int fc = t % NC_;
    int b = t / NC_;
    const bf16* p = depth + (size_t)b * F_ * S_ + (size_t)(fc * FC_) * S_ + s;
    float acc = 0.f;
#pragma unroll
    for (int f = 0; f < FC_; ++f) acc += __bfloat162float(p[(size_t)f * S_]);
    partials[idx] = acc;
}

__global__ void combine_apply(const float* __restrict__ inp, const float* __restrict__ divisor,
                              const bf16* __restrict__ depth, const bf16* __restrict__ point,
                              const bf16* __restrict__ shiftb,
                              const float* __restrict__ partials, float* __restrict__ y) {
    int idx = blockIdx.x * 256 + threadIdx.x;   // over B*NC*S
    int s = idx & (S_ - 1);
    int t = idx / S_;
    int fc = t % NC_;
    int b = t / NC_;
    float acc = 0.f;
    const float* pp = partials + (size_t)b * NC_ * S_ + s;
    for (int c = 0; c < fc; ++c) acc += pp[(size_t)c * S_];
    size_t base = (size_t)b * F_ * S_ + (size_t)(fc * FC_) * S_ + s;
#pragma unroll 4
    for (int f = 0; f < FC_; ++f) {
        size_t o = base + (size_t)f * S_;
        acc += __bfloat162float(depth[o]);
        float yv = inp[o] * (acc / divisor[fc * FC_ + f] + __bfloat162float(point[o]))
                 + __bfloat162float(shiftb[o]);
        y[o] = yv;
    }
}

__global__ void finalnorm(const float* __restrict__ y, const float2* __restrict__ stats,
                          float* __restrict__ out) {
    size_t i = (size_t)blockIdx.x * 256 + threadIdx.x;
    if (i >= (size_t)B_ * F_ * S_) return;
    float2 st = stats[i / S_];
    float v = fmaxf(y[i], 0.f);
    out[i] = (v - st.x) * st.y;
}

// ---------------------------------------------------------------------------
extern "C" void kernel_launch(void* const* d_in, const int* in_sizes, int n_in,
                              void* d_out, int out_size, void* d_ws, size_t ws_size,
                              hipStream_t stream) {
    const float* inp = (const float*)d_in[0];
    const float* pos = (const float*)d_in[1];
    const float* divisor = (const float*)d_in[2];
    const float* w[6] = { (const float*)d_in[3], (const float*)d_in[4],
                          (const float*)d_in[5], (const float*)d_in[6],
                          (const float*)d_in[7], (const float*)d_in[8] };
    float* out = (float*)d_out;

    size_t off = 0;
    auto alloc = [&](size_t bytes) {
        off = (off + 255) & ~(size_t)255;
        void* r = (char*)d_ws + off;
        off += bytes;
        return r;
    };

    // batched layout sizes
    const size_t needB = ((BSPF_ * 2 + 255) & ~255UL)            // xT
                       + ((3 * BSPF_ * 2 + 255) & ~255UL)        // hT3
                       + ((3 * 7 * FF_ * 2 + 255) & ~255UL)      // Wb3
                       + ((3 * BFS_ * 2 + 255) & ~255UL)         // O3 bf16
                       + ((3 * BFS_ * 2 + 255) & ~255UL)         // br3
                       + ((3 * B_ * F_ * 8 + 255) & ~255UL)      // stats3
                       + ((B_ * NC_ * S_ * 4 + 255) & ~255UL)    // partials
                       + 4096;

    if (ws_size >= needB) {
        // ---------------- batched path ----------------
        bf16* xT   = (bf16*)alloc(BSPF_ * 2);
        bf16* hT3  = (bf16*)alloc(3 * BSPF_ * 2);
        bf16* Wb3  = (bf16*)alloc(3 * 7 * FF_ * 2);
        bf16* O3   = (bf16*)alloc(3 * BFS_ * 2);
        bf16* br3  = (bf16*)alloc(3 * BFS_ * 2);
        float2* stats3 = (float2*)alloc(3 * B_ * F_ * 8);
        float* partials = (float*)alloc(B_ * NC_ * S_ * 4);
        float* ybuf = (float*)O3;   // O3 dead after normT; 50MB >= 33.5MB

        zero_pads<<<(4 * B_ * (K_ - 1) * F_ + 255) / 256, 256, 0, stream>>>(xT, hT3, 3);
        prep_x<<<dim3(S_ / 64, F_ / 64, B_), 256, 0, stream>>>(inp, pos, xT);

        for (int j = 0; j < 3; ++j)
            wconv<<<F_ * F_ / 256, 256, 0, stream>>>(w[2 * j], Wb3 + j * 7 * FF_);
        conv_gemm<bf16><<<16 * 8 * 12, 256, 0, stream>>>(Wb3, xT, O3,
                                                         7 * FF_, 0, BFS_);
        rowstats_bf16<<<3 * B_ * F_ / 4, 256, 0, stream>>>(O3, stats3);
        normT<<<dim3(S_ / 64, F_ / 64, 12), 256, 0, stream>>>(O3, stats3, hT3);

        for (int j = 0; j < 3; ++j)
            wconv<<<F_ * F_ / 256, 256, 0, stream>>>(w[2 * j + 1], Wb3 + j * 7 * FF_);
        conv_gemm<bf16><<<16 * 8 * 12, 256, 0, stream>>>(Wb3, hT3, br3,
                                                         7 * FF_, BSPF_, BFS_);

        combine_partial<<<B_ * NC_ * S_ / 256, 256, 0, stream>>>(br3, partials);
        combine_apply<<<B_ * NC_ * S_ / 256, 256, 0, stream>>>(
            inp, divisor, br3, br3 + BFS_, br3 + 2 * BFS_, partials, ybuf);
        rowstats_f32<<<B_ * F_ / 4, 256, 0, stream>>>(ybuf, stats3);
        finalnorm<<<(B_ * F_ * S_) / 256, 256, 0, stream>>>(ybuf, stats3, out);
    } else {
        // ---------------- sequential fallback (compact ws) ----------------
        bf16* xT   = (bf16*)alloc(BSPF_ * 2);
        bf16* hT1  = (bf16*)alloc(BSPF_ * 2);
        bf16* Wb1  = (bf16*)alloc(7 * FF_ * 2);
        bf16* O1   = (bf16*)alloc(BFS_ * 2);
        bf16* br3  = (bf16*)alloc(3 * BFS_ * 2);
        float2* stats3 = (float2*)alloc(B_ * F_ * 8);
        float* partials = (float*)alloc(B_ * NC_ * S_ * 4);
        float* ybuf = (float*)xT;   // xT+hT1 contiguous (both 256-aligned sizes), dead by combine

        zero_pads<<<(2 * B_ * (K_ - 1) * F_ + 255) / 256, 256, 0, stream>>>(xT, hT1, 1);
        prep_x<<<dim3(S_ / 64, F_ / 64, B_), 256, 0, stream>>>(inp, pos, xT);

        for (int j = 0; j < 3; ++j) {
            wconv<<<F_ * F_ / 256, 256, 0, stream>>>(w[2 * j], Wb1);
            conv_gemm<bf16><<<16 * 8 * 4, 256, 0, stream>>>(Wb1, xT, O1, 0, 0, 0);
            rowstats_bf16<<<B_ * F_ / 4, 256, 0, stream>>>(O1, stats3);
            normT<<<dim3(S_ / 64, F_ / 64, 4), 256, 0, stream>>>(O1, stats3, hT1);
            wconv<<<F_ * F_ / 256, 256, 0, stream>>>(w[2 * j + 1], Wb1);
            conv_gemm<bf16><<<16 * 8 * 4, 256, 0, stream>>>(Wb1, hT1, br3 + j * BFS_, 0, 0, 0);
        }
        combine_partial<<<B_ * NC_ * S_ / 256, 256, 0, stream>>>(br3, partials);
        combine_apply<<<B_ * NC_ * S_ / 256, 256, 0, stream>>>(
            inp, divisor, br3, br3 + BFS_, br3 + 2 * BFS_, partials, ybuf);
        rowstats_f32<<<B_ * F_ / 4, 256, 0, stream>>>(ybuf, stats3);
        finalnorm<<<(B_ * F_ * S_) / 256, 256, 0, stream>>>(ybuf, stats3, out);
    }
}

// Round 4
// 859.612 us; speedup vs baseline: 1.7339x; 1.0657x over previous
//
#include <hip/hip_runtime.h>
#include <hip/hip_bf16.h>
#include <stdint.h>

#define B_ 4
#define F_ 1024
#define S_ 2048
#define K_ 7
#define SP_ (S_ + K_ - 1)   // 2054 padded rows (6 zero rows at the front)
#define FC_ 64              // cumsum chunk size
#define NC_ (F_ / FC_)      // 16 chunks
#define FF_ ((size_t)F_ * F_)
#define BFS_ ((size_t)B_ * F_ * S_)
#define BSPF_ ((size_t)B_ * SP_ * F_)
#define NT_ 112             // K-tiles: 7 taps * (1024/64)

using f32x4 = __attribute__((ext_vector_type(4))) float;
using s16x8 = __attribute__((ext_vector_type(8))) short;
using bf16 = __hip_bfloat16;

// -------- async global->LDS 16B (wave-uniform base + lane*16 semantics) -----
typedef const __attribute__((address_space(1))) void gvoid_t;
typedef __attribute__((address_space(3))) void lvoid_t;
__device__ __forceinline__ void async16(const void* g, void* l) {
    __builtin_amdgcn_global_load_lds((gvoid_t*)g, (lvoid_t*)l, 16, 0, 0);
}

__device__ __forceinline__ float bf2f(unsigned short u) {
    union { unsigned int i; float f; } c; c.i = ((unsigned int)u) << 16; return c.f;
}

#define FENCE() asm volatile("" ::: "memory")
#define BARRIER() do { FENCE(); __builtin_amdgcn_s_barrier(); FENCE(); } while (0)

// ---------------------------------------------------------------------------
__global__ void zero_pads(bf16* xT, bf16* hT, int nh) {
    int i = blockIdx.x * 256 + threadIdx.x;
    const int per = B_ * (K_ - 1) * F_;
    int total = (1 + nh) * per;
    if (i >= total) return;
    int r = i / per, o = i % per;
    int b = o / ((K_ - 1) * F_);
    int rr = o % ((K_ - 1) * F_);
    bf16 z = __float2bfloat16(0.0f);
    if (r == 0) xT[(size_t)b * SP_ * F_ + rr] = z;
    else        hT[(size_t)(r - 1) * BSPF_ + (size_t)b * SP_ * F_ + rr] = z;
}

__global__ void prep_x(const float* __restrict__ inp, const float* __restrict__ pos,
                       bf16* __restrict__ xT) {
    __shared__ bf16 tile[64][66];
    int b = blockIdx.z;
    int f0 = blockIdx.y * 64, s0 = blockIdx.x * 64;
    int tj = threadIdx.x & 63;
    int t4 = threadIdx.x >> 6;
#pragma unroll
    for (int r = 0; r < 16; ++r) {
        int i = r * 4 + t4;
        size_t off = (size_t)(f0 + i) * S_ + s0 + tj;
        float v = inp[(size_t)b * F_ * S_ + off] + pos[off];
        tile[i][tj] = __float2bfloat16(v);
    }
    __syncthreads();
#pragma unroll
    for (int r = 0; r < 16; ++r) {
        int j = r * 4 + t4;
        xT[(size_t)b * SP_ * F_ + (size_t)(6 + s0 + j) * F_ + f0 + tj] = tile[tj][j];
    }
}

__global__ void wconv(const float* __restrict__ w, bf16* __restrict__ wt) {
    int i = blockIdx.x * 256 + threadIdx.x;
    if (i >= F_ * F_) return;
    const float* src = w + (size_t)i * K_;
#pragma unroll
    for (int t = 0; t < K_; ++t)
        wt[(size_t)t * FF_ + i] = __float2bfloat16(src[t]);
}

// ---------------------------------------------------------------------------
// 256x256x(7*1024) bf16 GEMM, 8-phase schedule (T2 st_16x32 swizzle + T3/T4
// counted vmcnt + T5 setprio). 8 waves (2M x 4N), BK=64, 128 KiB LDS dbuf.
// LDS per buf: A0[128][64] A1 B0 B1, each 16 KiB, 16x32-subtiled + bit9->bit5 XOR.
#define REG_A0 0
#define REG_A1 16384
#define REG_B0 32768
#define REG_B1 49152

#define MFMA_QUAD(MB, NB)                                                        \
    __builtin_amdgcn_s_setprio(1);                                               \
    _Pragma("unroll")                                                            \
    for (int kk = 0; kk < 2; ++kk) {                                             \
        _Pragma("unroll")                                                        \
        for (int m = 0; m < 4; ++m) {                                            \
            _Pragma("unroll")                                                    \
            for (int n = 0; n < 2; ++n) {                                        \
                acc[(MB) + m][(NB) + n] = __builtin_amdgcn_mfma_f32_16x16x32_bf16( \
                    af[m][kk], bf[(NB) + n][kk], acc[(MB) + m][(NB) + n], 0, 0, 0); \
            }                                                                    \
        }                                                                        \
    }                                                                            \
    __builtin_amdgcn_s_setprio(0)

__global__ __launch_bounds__(512, 2)
void conv_gemm8(const bf16* __restrict__ Wbase, const bf16* __restrict__ Xbase,
                bf16* __restrict__ Obase, long wStride, long xStride, long oStride) {
    __shared__ __align__(16) char lds[131072];

    // bijective XCD swizzle (384 % 8 == 0)
    int wg = blockIdx.x;
    int swz = (wg & 7) * 48 + (wg >> 3);
    int nt = swz & 7;           // S/256
    int mt = (swz >> 3) & 3;    // F/256
    int z  = swz >> 5;          // j*4 + b
    int j = z >> 2, b = z & 3;

    const bf16* Wbr = Wbase + (size_t)j * wStride;                       // [7][F][F]
    const bf16* Xbr = Xbase + (size_t)j * xStride + (size_t)b * SP_ * F_; // [SP][F]
    bf16* out = Obase + (size_t)j * oStride + (size_t)b * F_ * S_;
    const int m0 = mt * 256, n0 = nt * 256;

    const int tid = threadIdx.x;
    const int lane = tid & 63, wid = tid >> 6;
    const int wm = wid >> 2, wn = wid & 3;      // wave tile: rows wm*128, cols wn*64

    // ---- staging decode: linear LDS byte p -> source element offset (inverse swizzle)
    const int tid16 = tid * 16;
    const int p0 = tid16, p1 = 8192 + tid16;
    const int lp0 = p0 ^ (((p0 >> 9) & 1) << 5);
    const int lp1 = p1 ^ (((p1 >> 9) & 1) << 5);
    const int stgO0 = (((lp0 >> 11) << 4) + ((lp0 >> 6) & 15)) * F_
                    + (((lp0 >> 10) & 1) << 5) + ((lp0 & 63) >> 1);
    const int stgO1 = (((lp1 >> 11) << 4) + ((lp1 >> 6) & 15)) * F_
                    + (((lp1 >> 10) & 1) << 5) + ((lp1 & 63) >> 1);

    // ---- ds_read swizzled base offsets
    const int rA = lane & 15, cA = (lane >> 4) * 8;   // cA in {0,8,16,24}
    const int swzRC = (rA << 6) + (((cA << 1)) ^ (((rA >> 3) & 1) << 5));
    const int aOff = wm * 16384 + swzRC;                                   // region A[wm]
    const int bOff = REG_B0 + (wn >> 1) * 16384 + (wn & 1) * 8192 + swzRC; // region B[wn>>1]

    f32x4 acc[8][4] = {};
    s16x8 af[4][2], bf[4][2];

    auto STG = [&](int regionByte, const bf16* src) {
        async16(src + stgO0, lds + regionByte + tid16);
        async16(src + stgO1, lds + regionByte + 8192 + tid16);
    };
    auto ASRC = [&](int kt, int h) {
        return Wbr + (size_t)(kt >> 4) * FF_ + (size_t)(m0 + h * 128) * F_ + (kt & 15) * 64;
    };
    auto BSRC = [&](int kt, int h) {
        return Xbr + (size_t)(n0 + (kt >> 4) + h * 128) * F_ + (kt & 15) * 64;
    };

    // ---- prologue: kt0 all 4 half-tiles, then kt1 {B0,B1,A0}; A1(1) comes in ph1(0)
    STG(REG_A0, ASRC(0, 0)); STG(REG_A1, ASRC(0, 1));
    STG(REG_B0, BSRC(0, 0)); STG(REG_B1, BSRC(0, 1));
    STG(65536 + REG_B0, BSRC(1, 0)); STG(65536 + REG_B1, BSRC(1, 1));
    STG(65536 + REG_A0, ASRC(1, 0));
    asm volatile("s_waitcnt vmcnt(6)" ::: "memory");
    BARRIER();

    for (int kt = 0; kt < NT_; ++kt) {
        const int bufB = (kt & 1) << 16;
        const int nbufB = bufB ^ 65536;
        const char* la = lds + bufB + aOff;
        const char* lb = lds + bufB + bOff;

        // ---- phase 1: read A-mh0 + B-nh0; stage A1(kt+1) into other buf
#pragma unroll
        for (int m = 0; m < 4; ++m) {
            af[m][0] = *(const s16x8*)(la + m * 2048);
            af[m][1] = *(const s16x8*)(la + m * 2048 + 1024);
        }
#pragma unroll
        for (int n = 0; n < 2; ++n) {
            bf[n][0] = *(const s16x8*)(lb + n * 2048);
            bf[n][1] = *(const s16x8*)(lb + n * 2048 + 1024);
        }
        if (kt + 1 < NT_) STG(nbufB + REG_A1, ASRC(kt + 1, 1));
        BARRIER();
        MFMA_QUAD(0, 0);
        BARRIER();

        // ---- phase 2: read B-nh1
#pragma unroll
        for (int n = 0; n < 2; ++n) {
            bf[2 + n][0] = *(const s16x8*)(lb + (2 + n) * 2048);
            bf[2 + n][1] = *(const s16x8*)(lb + (2 + n) * 2048 + 1024);
        }
        BARRIER();
        MFMA_QUAD(0, 2);
        BARRIER();

        // ---- phase 3: read A-mh1; stage B0,B1(kt+2) into THIS buf (B last read ph2)
#pragma unroll
        for (int m = 0; m < 4; ++m) {
            af[m][0] = *(const s16x8*)(la + (4 + m) * 2048);
            af[m][1] = *(const s16x8*)(la + (4 + m) * 2048 + 1024);
        }
        if (kt + 2 < NT_) {
            STG(bufB + REG_B0, BSRC(kt + 2, 0));
            STG(bufB + REG_B1, BSRC(kt + 2, 1));
        }
        BARRIER();
        MFMA_QUAD(4, 0);
        BARRIER();

        // ---- phase 4: stage A0(kt+2) (A last read ph3); MFMA; counted vmcnt; barrier
        if (kt + 2 < NT_) STG(bufB + REG_A0, ASRC(kt + 2, 0));
        MFMA_QUAD(4, 2);
        if (kt < NT_ - 2) { asm volatile("s_waitcnt vmcnt(6)" ::: "memory"); }
        else              { asm volatile("s_waitcnt vmcnt(0)" ::: "memory"); }
        BARRIER();
    }

    // epilogue: C/D layout col=lane&15, row=(lane>>4)*4+reg  [m89-verified]
    const int cm = (lane >> 4) * 4, cn = lane & 15;
#pragma unroll
    for (int mf = 0; mf < 8; ++mf)
#pragma unroll
        for (int nf = 0; nf < 4; ++nf)
#pragma unroll
            for (int r = 0; r < 4; ++r) {
                int rr = m0 + wm * 128 + mf * 16 + cm + r;
                int cc = n0 + wn * 64 + nf * 16 + cn;
                out[(size_t)rr * S_ + cc] = __float2bfloat16(acc[mf][nf][r]);
            }
}

// ---------------- fallback 128x128 2-phase GEMM (small-ws path) -------------
__global__ void conv_gemm_small(const bf16* __restrict__ W7, const bf16* __restrict__ xT,
                                bf16* __restrict__ out) {
    __shared__ bf16 tA[128][64];
    __shared__ bf16 tB[128][64];
    int wg = blockIdx.x;
    int cpx = gridDim.x >> 3;
    int swz = (wg & 7) * cpx + (wg >> 3);
    int sx = swz & 15;
    int t1 = swz >> 4;
    int sy = t1 & 7;
    int b = t1 >> 3;
    const bf16* Xbr = xT + (size_t)b * SP_ * F_;
    bf16* ob = out + (size_t)b * F_ * S_;
    int m0 = sy * 128, n0 = sx * 128;
    int tid = threadIdx.x;
    int lane = tid & 63, wid = tid >> 6;
    int wm = wid >> 1, wn = wid & 1;
    f32x4 acc[4][4] = {};
    int srow = tid >> 3, cpart = tid & 7;
    for (int t = 0; t < K_; ++t) {
        const bf16* Wt = W7 + (size_t)t * FF_ + (size_t)m0 * F_;
        const bf16* Xt = Xbr + (size_t)(n0 + t) * F_;
        for (int kb = 0; kb < F_ / 64; ++kb) {
            const bf16* wa = Wt + kb * 64 + cpart * 8;
            const bf16* xa = Xt + kb * 64 + cpart * 8;
#pragma unroll
            for (int q = 0; q < 4; ++q) async16(wa + (size_t)(q * 32 + srow) * F_, &tA[q * 32 + srow][cpart * 8]);
#pragma unroll
            for (int q = 0; q < 4; ++q) async16(xa + (size_t)(q * 32 + srow) * F_, &tB[q * 32 + srow][cpart * 8]);
            __syncthreads();
#pragma unroll
            for (int kk = 0; kk < 2; ++kk) {
                int krow = kk * 32 + (lane >> 4) * 8;
                s16x8 a2[4], b2[4];
#pragma unroll
                for (int m = 0; m < 4; ++m) a2[m] = *(const s16x8*)&tA[wm * 64 + m * 16 + (lane & 15)][krow];
#pragma unroll
                for (int n = 0; n < 4; ++n) b2[n] = *(const s16x8*)&tB[wn * 64 + n * 16 + (lane & 15)][krow];
#pragma unroll
                for (int m = 0; m < 4; ++m)
#pragma unroll
                    for (int n = 0; n < 4; ++n)
                        acc[m][n] = __builtin_amdgcn_mfma_f32_16x16x32_bf16(a2[m], b2[n], acc[m][n], 0, 0, 0);
            }
            __syncthreads();
        }
    }
    int cm = (lane >> 4) * 4, cn = lane & 15;
#pragma unroll
    for (int m = 0; m < 4; ++m)
#pragma unroll
        for (int n = 0; n < 4; ++n)
#pragma unroll
            for (int r = 0; r < 4; ++r)
                ob[(size_t)(m0 + wm * 64 + m * 16 + cm + r) * S_ + n0 + wn * 64 + n * 16 + cn] =
                    __float2bfloat16(acc[m][n][r]);
}

// ---------------------------------------------------------------------------
__global__ void rowstats_bf16(const bf16* __restrict__ x, float2* __restrict__ stats) {
    int row = blockIdx.x * 4 + (threadIdx.x >> 6);
    int lane = threadIdx.x & 63;
    const bf16* p = x + (size_t)row * S_;
    float s1 = 0.f, s2 = 0.f;
#pragma unroll
    for (int q = 0; q < S_ / 512; ++q) {
        s16x8 v = *(const s16x8*)(p + q * 512 + lane * 8);
#pragma unroll
        for (int e = 0; e < 8; ++e) {
            float f = fmaxf(bf2f((unsigned short)v[e]), 0.f);
            s1 += f; s2 += f * f;
        }
    }
#pragma unroll
    for (int d = 32; d; d >>= 1) { s1 += __shfl_xor(s1, d); s2 += __shfl_xor(s2, d); }
    if (lane == 0) {
        float m = s1 / (float)S_;
        float ss = fmaxf(s2 - (float)S_ * m * m, 0.f);
        float denom = (sqrtf(ss) + 1e-5f) * (1.0f / sqrtf((float)S_));
        stats[row] = make_float2(m, 1.0f / denom);
    }
}

__global__ void rowstats_f32(const float* __restrict__ x, float2* __restrict__ stats) {
    int row = blockIdx.x * 4 + (threadIdx.x >> 6);
    int lane = threadIdx.x & 63;
    const float* p = x + (size_t)row * S_;
    float s1 = 0.f, s2 = 0.f;
#pragma unroll
    for (int q = 0; q < S_; q += 256) {
        float4 v = *(const float4*)(p + q + lane * 4);
        float a = fmaxf(v.x, 0.f), bb = fmaxf(v.y, 0.f);
        float c = fmaxf(v.z, 0.f), d = fmaxf(v.w, 0.f);
        s1 += a + bb + c + d;
        s2 += a * a + bb * bb + c * c + d * d;
    }
#pragma unroll
    for (int d = 32; d; d >>= 1) { s1 += __shfl_xor(s1, d); s2 += __shfl_xor(s2, d); }
    if (lane == 0) {
        float m = s1 / (float)S_;
        float ss = fmaxf(s2 - (float)S_ * m * m, 0.f);
        float denom = (sqrtf(ss) + 1e-5f) * (1.0f / sqrtf((float)S_));
        stats[row] = make_float2(m, 1.0f / denom);
    }
}

__global__ void normT(const bf16* __restrict__ x, const float2* __restrict__ stats,
                      bf16* __restrict__ hT) {
    __shared__ bf16 tile[64][72];
    int z = blockIdx.z;
    int f0 = blockIdx.y * 64, s0 = blockIdx.x * 64;
    const bf16* xb = x + (size_t)z * F_ * S_;
    bf16* hb = hT + (size_t)z * SP_ * F_;
    const float2* st = stats + (size_t)z * F_;
    int i = threadIdx.x >> 3;
    int c8 = threadIdx.x & 7;
#pragma unroll
    for (int p = 0; p < 2; ++p) {
        int r = i + p * 32;
        float2 s = st[f0 + r];
        s16x8 v = *(const s16x8*)(xb + (size_t)(f0 + r) * S_ + s0 + c8 * 8);
#pragma unroll
        for (int e = 0; e < 8; ++e) {
            float f = fmaxf(bf2f((unsigned short)v[e]), 0.f);
            tile[r][c8 * 8 + e] = __float2bfloat16((f - s.x) * s.y);
        }
    }
    __syncthreads();
    int tj = threadIdx.x & 63;
    int t4 = threadIdx.x >> 6;
#pragma unroll
    for (int r = 0; r < 16; ++r) {
        int jrow = r * 4 + t4;
        hb[(size_t)(6 + s0 + jrow) * F_ + f0 + tj] = tile[tj][jrow];
    }
}

__global__ void combine_partial(const bf16* __restrict__ depth,
                                float* __restrict__ partials) {
    int idx = blockIdx.x * 256 + threadIdx.x;
    int s = idx & (S_ - 1);
    int t = idx / S_;
    int fc = t % NC_;
    int b = t / NC_;
    const bf16* p = depth + (size_t)b * F_ * S_ + (size_t)(fc * FC_) * S_ + s;
    float acc = 0.f;
#pragma unroll
    for (int f = 0; f < FC_; ++f) acc += __bfloat162float(p[(size_t)f * S_]);
    partials[idx] = acc;
}

__global__ void combine_apply(const float* __restrict__ inp, const float* __restrict__ divisor,
                              const bf16* __restrict__ depth, const bf16* __restrict__ point,
                              const bf16* __restrict__ shiftb,
                              const float* __restrict__ partials, float* __restrict__ y) {
    int idx = blockIdx.x * 256 + threadIdx.x;
    int s = idx & (S_ - 1);
    int t = idx / S_;
    int fc = t % NC_;
    int b = t / NC_;
    float acc = 0.f;
    const float* pp = partials + (size_t)b * NC_ * S_ + s;
    for (int c = 0; c < fc; ++c) acc += pp[(size_t)c * S_];
    size_t base = (size_t)b * F_ * S_ + (size_t)(fc * FC_) * S_ + s;
#pragma unroll 4
    for (int f = 0; f < FC_; ++f) {
        size_t o = base + (size_t)f * S_;
        acc += __bfloat162float(depth[o]);
        float yv = inp[o] * (acc / divisor[fc * FC_ + f] + __bfloat162float(point[o]))
                 + __bfloat162float(shiftb[o]);
        y[o] = yv;
    }
}

__global__ void finalnorm(const float* __restrict__ y, const float2* __restrict__ stats,
                          float* __restrict__ out) {
    size_t i = (size_t)blockIdx.x * 256 + threadIdx.x;
    if (i >= (size_t)B_ * F_ * S_) return;
    float2 st = stats[i / S_];
    float v = fmaxf(y[i], 0.f);
    out[i] = (v - st.x) * st.y;
}

// ---------------------------------------------------------------------------
extern "C" void kernel_launch(void* const* d_in, const int* in_sizes, int n_in,
                              void* d_out, int out_size, void* d_ws, size_t ws_size,
                              hipStream_t stream) {
    const float* inp = (const float*)d_in[0];
    const float* pos = (const float*)d_in[1];
    const float* divisor = (const float*)d_in[2];
    const float* w[6] = { (const float*)d_in[3], (const float*)d_in[4],
                          (const float*)d_in[5], (const float*)d_in[6],
                          (const float*)d_in[7], (const float*)d_in[8] };
    float* out = (float*)d_out;

    size_t off = 0;
    auto alloc = [&](size_t bytes) {
        off = (off + 255) & ~(size_t)255;
        void* r = (char*)d_ws + off;
        off += bytes;
        return r;
    };

    const size_t needB = ((BSPF_ * 2 + 255) & ~255UL)
                       + ((3 * BSPF_ * 2 + 255) & ~255UL)
                       + ((3 * 7 * FF_ * 2 + 255) & ~255UL)
                       + ((3 * BFS_ * 2 + 255) & ~255UL)
                       + ((3 * BFS_ * 2 + 255) & ~255UL)
                       + ((3 * B_ * F_ * 8 + 255) & ~255UL)
                       + ((B_ * NC_ * S_ * 4 + 255) & ~255UL)
                       + 4096;

    if (ws_size >= needB) {
        bf16* xT   = (bf16*)alloc(BSPF_ * 2);
        bf16* hT3  = (bf16*)alloc(3 * BSPF_ * 2);
        bf16* Wb3  = (bf16*)alloc(3 * 7 * FF_ * 2);
        bf16* O3   = (bf16*)alloc(3 * BFS_ * 2);
        bf16* br3  = (bf16*)alloc(3 * BFS_ * 2);
        float2* stats3 = (float2*)alloc(3 * B_ * F_ * 8);
        float* partials = (float*)alloc(B_ * NC_ * S_ * 4);
        float* ybuf = (float*)O3;   // O3 dead after normT

        zero_pads<<<(4 * B_ * (K_ - 1) * F_ + 255) / 256, 256, 0, stream>>>(xT, hT3, 3);
        prep_x<<<dim3(S_ / 64, F_ / 64, B_), 256, 0, stream>>>(inp, pos, xT);

        for (int j = 0; j < 3; ++j)
            wconv<<<F_ * F_ / 256, 256, 0, stream>>>(w[2 * j], Wb3 + j * 7 * FF_);
        conv_gemm8<<<384, 512, 0, stream>>>(Wb3, xT, O3, 7 * FF_, 0, BFS_);
        rowstats_bf16<<<3 * B_ * F_ / 4, 256, 0, stream>>>(O3, stats3);
        normT<<<dim3(S_ / 64, F_ / 64, 12), 256, 0, stream>>>(O3, stats3, hT3);

        for (int j = 0; j < 3; ++j)
            wconv<<<F_ * F_ / 256, 256, 0, stream>>>(w[2 * j + 1], Wb3 + j * 7 * FF_);
        conv_gemm8<<<384, 512, 0, stream>>>(Wb3, hT3, br3, 7 * FF_, BSPF_, BFS_);

        combine_partial<<<B_ * NC_ * S_ / 256, 256, 0, stream>>>(br3, partials);
        combine_apply<<<B_ * NC_ * S_ / 256, 256, 0, stream>>>(
            inp, divisor, br3, br3 + BFS_, br3 + 2 * BFS_, partials, ybuf);
        rowstats_f32<<<B_ * F_ / 4, 256, 0, stream>>>(ybuf, stats3);
        finalnorm<<<(B_ * F_ * S_) / 256, 256, 0, stream>>>(ybuf, stats3, out);
    } else {
        // sequential fallback (compact ws), proven path
        bf16* xT   = (bf16*)alloc(BSPF_ * 2);
        bf16* hT1  = (bf16*)alloc(BSPF_ * 2);
        bf16* Wb1  = (bf16*)alloc(7 * FF_ * 2);
        bf16* O1   = (bf16*)alloc(BFS_ * 2);
        bf16* br3  = (bf16*)alloc(3 * BFS_ * 2);
        float2* stats3 = (float2*)alloc(B_ * F_ * 8);
        float* partials = (float*)alloc(B_ * NC_ * S_ * 4);
        float* ybuf = (float*)xT;

        zero_pads<<<(2 * B_ * (K_ - 1) * F_ + 255) / 256, 256, 0, stream>>>(xT, hT1, 1);
        prep_x<<<dim3(S_ / 64, F_ / 64, B_), 256, 0, stream>>>(inp, pos, xT);

        for (int j = 0; j < 3; ++j) {
            wconv<<<F_ * F_ / 256, 256, 0, stream>>>(w[2 * j], Wb1);
            conv_gemm_small<<<16 * 8 * 4, 256, 0, stream>>>(Wb1, xT, O1);
            rowstats_bf16<<<B_ * F_ / 4, 256, 0, stream>>>(O1, stats3);
            normT<<<dim3(S_ / 64, F_ / 64, 4), 256, 0, stream>>>(O1, stats3, hT1);
            wconv<<<F_ * F_ / 256, 256, 0, stream>>>(w[2 * j + 1], Wb1);
            conv_gemm_small<<<16 * 8 * 4, 256, 0, stream>>>(Wb1, hT1, br3 + j * BFS_);
        }
        combine_partial<<<B_ * NC_ * S_ / 256, 256, 0, stream>>>(br3, partials);
        combine_apply<<<B_ * NC_ * S_ / 256, 256, 0, stream>>>(
            inp, divisor, br3, br3 + BFS_, br3 + 2 * BFS_, partials, ybuf);
        rowstats_f32<<<B_ * F_ / 4, 256, 0, stream>>>(ybuf, stats3);
        finalnorm<<<(B_ * F_ * S_) / 256, 256, 0, stream>>>(ybuf, stats3, out);
    }
}

// Round 5
// 795.508 us; speedup vs baseline: 1.8737x; 1.0806x over previous
//
#include <hip/hip_runtime.h>
#include <hip/hip_bf16.h>
#include <stdint.h>

#define B_ 4
#define F_ 1024
#define S_ 2048
#define K_ 7
#define SP_ (S_ + K_ - 1)   // 2054 padded rows (6 zero rows at the front)
#define FC_ 64              // cumsum chunk size
#define NC_ (F_ / FC_)      // 16 chunks
#define FF_ ((size_t)F_ * F_)
#define BFS_ ((size_t)B_ * F_ * S_)
#define BSPF_ ((size_t)B_ * SP_ * F_)
#define NT_ 112             // K-tiles: 16 kb * 7 taps (kb-major order)

using f32x4 = __attribute__((ext_vector_type(4))) float;
using s16x8 = __attribute__((ext_vector_type(8))) short;
using bf16 = __hip_bfloat16;

// -------- async global->LDS 16B (wave-uniform base + lane*16 semantics) -----
typedef const __attribute__((address_space(1))) void gvoid_t;
typedef __attribute__((address_space(3))) void lvoid_t;
__device__ __forceinline__ void async16(const void* g, void* l) {
    __builtin_amdgcn_global_load_lds((gvoid_t*)g, (lvoid_t*)l, 16, 0, 0);
}

__device__ __forceinline__ float bf2f(unsigned short u) {
    union { unsigned int i; float f; } c; c.i = ((unsigned int)u) << 16; return c.f;
}

#define FENCE() asm volatile("" ::: "memory")
#define BARRIER() do { FENCE(); __builtin_amdgcn_s_barrier(); FENCE(); } while (0)

// ---------------------------------------------------------------------------
__global__ void zero_pads(bf16* xT, bf16* hT, int nh) {
    int i = blockIdx.x * 256 + threadIdx.x;
    const int per = B_ * (K_ - 1) * F_;
    int total = (1 + nh) * per;
    if (i >= total) return;
    int r = i / per, o = i % per;
    int b = o / ((K_ - 1) * F_);
    int rr = o % ((K_ - 1) * F_);
    bf16 z = __float2bfloat16(0.0f);
    if (r == 0) xT[(size_t)b * SP_ * F_ + rr] = z;
    else        hT[(size_t)(r - 1) * BSPF_ + (size_t)b * SP_ * F_ + rr] = z;
}

__global__ void prep_x(const float* __restrict__ inp, const float* __restrict__ pos,
                       bf16* __restrict__ xT) {
    __shared__ bf16 tile[64][66];
    int b = blockIdx.z;
    int f0 = blockIdx.y * 64, s0 = blockIdx.x * 64;
    int tj = threadIdx.x & 63;
    int t4 = threadIdx.x >> 6;
#pragma unroll
    for (int r = 0; r < 16; ++r) {
        int i = r * 4 + t4;
        size_t off = (size_t)(f0 + i) * S_ + s0 + tj;
        float v = inp[(size_t)b * F_ * S_ + off] + pos[off];
        tile[i][tj] = __float2bfloat16(v);
    }
    __syncthreads();
#pragma unroll
    for (int r = 0; r < 16; ++r) {
        int j = r * 4 + t4;
        xT[(size_t)b * SP_ * F_ + (size_t)(6 + s0 + j) * F_ + f0 + tj] = tile[tj][j];
    }
}

__global__ void wconv(const float* __restrict__ w, bf16* __restrict__ wt) {
    int i = blockIdx.x * 256 + threadIdx.x;
    if (i >= F_ * F_) return;
    const float* src = w + (size_t)i * K_;
#pragma unroll
    for (int t = 0; t < K_; ++t)
        wt[(size_t)t * FF_ + i] = __float2bfloat16(src[t]);
}

// ---------------------------------------------------------------------------
// 256x256 bf16 conv-GEMM, 8-phase schedule, kb-major K-order with SHARED
// B-panel across the 7 taps (tap = shifted LDS read). LDS 144 KiB:
//   A: 2 bufs x (A0[128rows] + A1[128rows]) x 64k = 2x32KB @ 0
//   B: 2 bufs x 320 rows x 64k              = 2x40KB @ 65536
// st_16x32 subtile layout + bit9->bit5 XOR swizzle on both A and B.
#define MFMA_QUAD(MB, NB)                                                        \
    __builtin_amdgcn_s_setprio(1);                                               \
    _Pragma("unroll")                                                            \
    for (int kk = 0; kk < 2; ++kk) {                                             \
        _Pragma("unroll")                                                        \
        for (int m = 0; m < 4; ++m) {                                            \
            _Pragma("unroll")                                                    \
            for (int n = 0; n < 2; ++n) {                                        \
                acc[(MB) + m][(NB) + n] = __builtin_amdgcn_mfma_f32_16x16x32_bf16( \
                    af[m][kk], bfr[(NB) + n][kk], acc[(MB) + m][(NB) + n], 0, 0, 0); \
            }                                                                    \
        }                                                                        \
    }                                                                            \
    __builtin_amdgcn_s_setprio(0)

__global__ __launch_bounds__(512, 2)
void conv_gemm8(const bf16* __restrict__ Wbase, const bf16* __restrict__ Xbase,
                bf16* __restrict__ Obase, long wStride, long xStride, long oStride) {
    __shared__ __align__(16) char lds[147456];

    // bijective XCD swizzle (384 % 8 == 0)
    int wg = blockIdx.x;
    int swz = (wg & 7) * 48 + (wg >> 3);
    int nt = swz & 7;           // S/256
    int mt = (swz >> 3) & 3;    // F/256
    int z  = swz >> 5;          // j*4 + b
    int j = z >> 2, b = z & 3;

    const bf16* Wbr = Wbase + (size_t)j * wStride;                        // [7][F][F]
    const bf16* Xbr = Xbase + (size_t)j * xStride + (size_t)b * SP_ * F_; // [SP][F]
    bf16* out = Obase + (size_t)j * oStride + (size_t)b * F_ * S_;
    const int m0 = mt * 256, n0 = nt * 256;

    const int tid = threadIdx.x;
    const int lane = tid & 63, wid = tid >> 6;
    const int wm = wid >> 2, wn = wid & 3;      // wave tile: rows wm*128, cols wn*64

    // ---- staging decode: linear LDS byte -> source element offset (inverse swizzle)
    const int tid16 = tid * 16;
    const int p0 = tid16, p1 = 8192 + tid16;
    const int lp0 = p0 ^ (((p0 >> 9) & 1) << 5);
    const int lp1 = p1 ^ (((p1 >> 9) & 1) << 5);
    const int stgO0 = (((lp0 >> 11) << 4) + ((lp0 >> 6) & 15)) * F_
                    + (((lp0 >> 10) & 1) << 5) + ((lp0 & 63) >> 1);
    const int stgO1 = (((lp1 >> 11) << 4) + ((lp1 >> 6) & 15)) * F_
                    + (((lp1 >> 10) & 1) << 5) + ((lp1 & 63) >> 1);
    // B piece decode: piece pc covers 64 rows; src elem = bsrc + pc*64*F
    const int bsrc = (((tid16 >> 11) << 4) + ((lp0 >> 6) & 15)) * F_
                   + (((lp0 >> 10) & 1) << 5) + ((lp0 & 63) >> 1);

    // ---- ds_read swizzled offsets
    const int rA = lane & 15, cA = (lane >> 4) * 8;
    const int swzRC = (rA << 6) + ((cA << 1) ^ (((rA >> 3) & 1) << 5));
    const int aOffBase = wm * 16384 + swzRC;
    int addrB[7];
#pragma unroll
    for (int t = 0; t < 7; ++t) {
        int R = wn * 64 + rA + t;           // shifted B row (tap t)
        addrB[t] = ((R >> 4) << 11) + ((R & 15) << 6)
                 + ((cA << 1) ^ (((R >> 3) & 1) << 5));
    }

    f32x4 acc[8][4] = {};
    s16x8 af[4][2], bfr[4][2];

    auto STGA = [&](int regionByte, const bf16* src) {   // 16KB region, 2 loads
        async16(src + stgO0, lds + regionByte + tid16);
        async16(src + stgO1, lds + regionByte + 8192 + tid16);
    };
    auto STGB = [&](int kb1, int pc) {                   // 8KB piece, 1 load
        const bf16* src = Xbr + (size_t)n0 * F_ + kb1 * 64 + bsrc + pc * 64 * F_;
        async16(src, lds + 65536 + (kb1 & 1) * 40960 + pc * 8192 + tid16);
    };
    auto ASRC = [&](int kb, int t, int h) {
        return Wbr + (size_t)t * FF_ + (size_t)(m0 + h * 128) * F_ + kb * 64;
    };

    // ---- prologue: B(kb0) whole, A(kt0) both halves, A0(kt1). keep-2 = A0(kt1)
    STGB(0, 0); STGB(0, 1); STGB(0, 2); STGB(0, 3); STGB(0, 4);
    STGA(0,     ASRC(0, 0, 0));     // A0(kt0) buf0
    STGA(16384, ASRC(0, 0, 1));     // A1(kt0) buf0
    STGA(32768, ASRC(0, 1, 0));     // A0(kt1) buf1
    asm volatile("s_waitcnt vmcnt(2)" ::: "memory");
    BARRIER();

    for (int kb = 0; kb < 16; ++kb) {
        const int bB = 65536 + (kb & 1) * 40960;
#pragma unroll
        for (int t = 0; t < 7; ++t) {
            const int kt = kb * 7 + t;
            const int pA = (kb + t) & 1;                 // (kb*7+t)&1
            const char* la = lds + pA * 32768 + aOffBase;
            const char* lb = lds + bB + addrB[t];
            const int t1 = (t == 6) ? 0 : t + 1;         // kt+1 decomposition
            const int kb1 = (t == 6) ? kb + 1 : kb;
            const int t2 = (t >= 5) ? t - 5 : t + 2;     // kt+2 decomposition
            const int kb2 = (t >= 5) ? kb + 1 : kb;

            // ---- phase 1: read A-mh0 + B-nh0; stage A1(kt+1) into other A-buf
#pragma unroll
            for (int m = 0; m < 4; ++m) {
                af[m][0] = *(const s16x8*)(la + m * 2048);
                af[m][1] = *(const s16x8*)(la + m * 2048 + 1024);
            }
#pragma unroll
            for (int n = 0; n < 2; ++n) {
                bfr[n][0] = *(const s16x8*)(lb + n * 2048);
                bfr[n][1] = *(const s16x8*)(lb + n * 2048 + 1024);
            }
            if (kt + 1 < NT_) STGA((pA ^ 1) * 32768 + 16384, ASRC(kb1, t1, 1));
            BARRIER();
            MFMA_QUAD(0, 0);
            BARRIER();

            // ---- phase 2: read B-nh1; stage one B(kb+1) piece (t=1..5)
#pragma unroll
            for (int n = 0; n < 2; ++n) {
                bfr[2 + n][0] = *(const s16x8*)(lb + (2 + n) * 2048);
                bfr[2 + n][1] = *(const s16x8*)(lb + (2 + n) * 2048 + 1024);
            }
            if (t >= 1 && t <= 5) { if (kb < 15) STGB(kb + 1, t - 1); }
            BARRIER();
            MFMA_QUAD(0, 2);
            BARRIER();

            // ---- phase 3: read A-mh1
#pragma unroll
            for (int m = 0; m < 4; ++m) {
                af[m][0] = *(const s16x8*)(la + (4 + m) * 2048);
                af[m][1] = *(const s16x8*)(la + (4 + m) * 2048 + 1024);
            }
            BARRIER();
            MFMA_QUAD(4, 0);
            BARRIER();

            // ---- phase 4: stage A0(kt+2) into this A-buf; MFMA; counted vmcnt
            if (kt + 2 < NT_) STGA(pA * 32768, ASRC(kb2, t2, 0));
            MFMA_QUAD(4, 2);
            if (kt < NT_ - 2) {
                if (t >= 1 && t <= 5 && kb < 15) {
                    asm volatile("s_waitcnt vmcnt(3)" ::: "memory");  // keep A0(kt+2)+Bp
                } else {
                    asm volatile("s_waitcnt vmcnt(2)" ::: "memory");  // keep A0(kt+2)
                }
            } else {
                asm volatile("s_waitcnt vmcnt(0)" ::: "memory");
            }
            BARRIER();
        }
    }

    // epilogue: C/D layout col=lane&15, row=(lane>>4)*4+reg  [m89-verified]
    const int cm = (lane >> 4) * 4, cn = lane & 15;
#pragma unroll
    for (int mf = 0; mf < 8; ++mf)
#pragma unroll
        for (int nf = 0; nf < 4; ++nf)
#pragma unroll
            for (int r = 0; r < 4; ++r) {
                int rr = m0 + wm * 128 + mf * 16 + cm + r;
                int cc = n0 + wn * 64 + nf * 16 + cn;
                out[(size_t)rr * S_ + cc] = __float2bfloat16(acc[mf][nf][r]);
            }
}

// ---------------- fallback 128x128 2-phase GEMM (small-ws path) -------------
__global__ void conv_gemm_small(const bf16* __restrict__ W7, const bf16* __restrict__ xT,
                                bf16* __restrict__ out) {
    __shared__ bf16 tA[128][64];
    __shared__ bf16 tB[128][64];
    int wg = blockIdx.x;
    int cpx = gridDim.x >> 3;
    int swz = (wg & 7) * cpx + (wg >> 3);
    int sx = swz & 15;
    int t1 = swz >> 4;
    int sy = t1 & 7;
    int b = t1 >> 3;
    const bf16* Xbr = xT + (size_t)b * SP_ * F_;
    bf16* ob = out + (size_t)b * F_ * S_;
    int m0 = sy * 128, n0 = sx * 128;
    int tid = threadIdx.x;
    int lane = tid & 63, wid = tid >> 6;
    int wm = wid >> 1, wn = wid & 1;
    f32x4 acc[4][4] = {};
    int srow = tid >> 3, cpart = tid & 7;
    for (int t = 0; t < K_; ++t) {
        const bf16* Wt = W7 + (size_t)t * FF_ + (size_t)m0 * F_;
        const bf16* Xt = Xbr + (size_t)(n0 + t) * F_;
        for (int kb = 0; kb < F_ / 64; ++kb) {
            const bf16* wa = Wt + kb * 64 + cpart * 8;
            const bf16* xa = Xt + kb * 64 + cpart * 8;
#pragma unroll
            for (int q = 0; q < 4; ++q) async16(wa + (size_t)(q * 32 + srow) * F_, &tA[q * 32 + srow][cpart * 8]);
#pragma unroll
            for (int q = 0; q < 4; ++q) async16(xa + (size_t)(q * 32 + srow) * F_, &tB[q * 32 + srow][cpart * 8]);
            __syncthreads();
#pragma unroll
            for (int kk = 0; kk < 2; ++kk) {
                int krow = kk * 32 + (lane >> 4) * 8;
                s16x8 a2[4], b2[4];
#pragma unroll
                for (int m = 0; m < 4; ++m) a2[m] = *(const s16x8*)&tA[wm * 64 + m * 16 + (lane & 15)][krow];
#pragma unroll
                for (int n = 0; n < 4; ++n) b2[n] = *(const s16x8*)&tB[wn * 64 + n * 16 + (lane & 15)][krow];
#pragma unroll
                for (int m = 0; m < 4; ++m)
#pragma unroll
                    for (int n = 0; n < 4; ++n)
                        acc[m][n] = __builtin_amdgcn_mfma_f32_16x16x32_bf16(a2[m], b2[n], acc[m][n], 0, 0, 0);
            }
            __syncthreads();
        }
    }
    int cm = (lane >> 4) * 4, cn = lane & 15;
#pragma unroll
    for (int m = 0; m < 4; ++m)
#pragma unroll
        for (int n = 0; n < 4; ++n)
#pragma unroll
            for (int r = 0; r < 4; ++r)
                ob[(size_t)(m0 + wm * 64 + m * 16 + cm + r) * S_ + n0 + wn * 64 + n * 16 + cn] =
                    __float2bfloat16(acc[m][n][r]);
}

// ---------------------------------------------------------------------------
__global__ void rowstats_bf16(const bf16* __restrict__ x, float2* __restrict__ stats) {
    int row = blockIdx.x * 4 + (threadIdx.x >> 6);
    int lane = threadIdx.x & 63;
    const bf16* p = x + (size_t)row * S_;
    float s1 = 0.f, s2 = 0.f;
#pragma unroll
    for (int q = 0; q < S_ / 512; ++q) {
        s16x8 v = *(const s16x8*)(p + q * 512 + lane * 8);
#pragma unroll
        for (int e = 0; e < 8; ++e) {
            float f = fmaxf(bf2f((unsigned short)v[e]), 0.f);
            s1 += f; s2 += f * f;
        }
    }
#pragma unroll
    for (int d = 32; d; d >>= 1) { s1 += __shfl_xor(s1, d); s2 += __shfl_xor(s2, d); }
    if (lane == 0) {
        float m = s1 / (float)S_;
        float ss = fmaxf(s2 - (float)S_ * m * m, 0.f);
        float denom = (sqrtf(ss) + 1e-5f) * (1.0f / sqrtf((float)S_));
        stats[row] = make_float2(m, 1.0f / denom);
    }
}

__global__ void rowstats_f32(const float* __restrict__ x, float2* __restrict__ stats) {
    int row = blockIdx.x * 4 + (threadIdx.x >> 6);
    int lane = threadIdx.x & 63;
    const float* p = x + (size_t)row * S_;
    float s1 = 0.f, s2 = 0.f;
#pragma unroll
    for (int q = 0; q < S_; q += 256) {
        float4 v = *(const float4*)(p + q + lane * 4);
        float a = fmaxf(v.x, 0.f), bb = fmaxf(v.y, 0.f);
        float c = fmaxf(v.z, 0.f), d = fmaxf(v.w, 0.f);
        s1 += a + bb + c + d;
        s2 += a * a + bb * bb + c * c + d * d;
    }
#pragma unroll
    for (int d = 32; d; d >>= 1) { s1 += __shfl_xor(s1, d); s2 += __shfl_xor(s2, d); }
    if (lane == 0) {
        float m = s1 / (float)S_;
        float ss = fmaxf(s2 - (float)S_ * m * m, 0.f);
        float denom = (sqrtf(ss) + 1e-5f) * (1.0f / sqrtf((float)S_));
        stats[row] = make_float2(m, 1.0f / denom);
    }
}

__global__ void normT(const bf16* __restrict__ x, const float2* __restrict__ stats,
                      bf16* __restrict__ hT) {
    __shared__ bf16 tile[64][72];
    int z = blockIdx.z;
    int f0 = blockIdx.y * 64, s0 = blockIdx.x * 64;
    const bf16* xb = x + (size_t)z * F_ * S_;
    bf16* hb = hT + (size_t)z * SP_ * F_;
    const float2* st = stats + (size_t)z * F_;
    int i = threadIdx.x >> 3;
    int c8 = threadIdx.x & 7;
#pragma unroll
    for (int p = 0; p < 2; ++p) {
        int r = i + p * 32;
        float2 s = st[f0 + r];
        s16x8 v = *(const s16x8*)(xb + (size_t)(f0 + r) * S_ + s0 + c8 * 8);
#pragma unroll
        for (int e = 0; e < 8; ++e) {
            float f = fmaxf(bf2f((unsigned short)v[e]), 0.f);
            tile[r][c8 * 8 + e] = __float2bfloat16((f - s.x) * s.y);
        }
    }
    __syncthreads();
    int tj = threadIdx.x & 63;
    int t4 = threadIdx.x >> 6;
#pragma unroll
    for (int r = 0; r < 16; ++r) {
        int jrow = r * 4 + t4;
        hb[(size_t)(6 + s0 + jrow) * F_ + f0 + tj] = tile[tj][jrow];
    }
}

__global__ void combine_partial(const bf16* __restrict__ depth,
                                float* __restrict__ partials) {
    int idx = blockIdx.x * 256 + threadIdx.x;
    int s = idx & (S_ - 1);
    int t = idx / S_;
    int fc = t % NC_;
    int b = t / NC_;
    const bf16* p = depth + (size_t)b * F_ * S_ + (size_t)(fc * FC_) * S_ + s;
    float acc = 0.f;
#pragma unroll
    for (int f = 0; f < FC_; ++f) acc += __bfloat162float(p[(size_t)f * S_]);
    partials[idx] = acc;
}

__global__ void combine_apply(const float* __restrict__ inp, const float* __restrict__ divisor,
                              const bf16* __restrict__ depth, const bf16* __restrict__ point,
                              const bf16* __restrict__ shiftb,
                              const float* __restrict__ partials, float* __restrict__ y) {
    int idx = blockIdx.x * 256 + threadIdx.x;
    int s = idx & (S_ - 1);
    int t = idx / S_;
    int fc = t % NC_;
    int b = t / NC_;
    float acc = 0.f;
    const float* pp = partials + (size_t)b * NC_ * S_ + s;
    for (int c = 0; c < fc; ++c) acc += pp[(size_t)c * S_];
    size_t base = (size_t)b * F_ * S_ + (size_t)(fc * FC_) * S_ + s;
#pragma unroll 4
    for (int f = 0; f < FC_; ++f) {
        size_t o = base + (size_t)f * S_;
        acc += __bfloat162float(depth[o]);
        float yv = inp[o] * (acc / divisor[fc * FC_ + f] + __bfloat162float(point[o]))
                 + __bfloat162float(shiftb[o]);
        y[o] = yv;
    }
}

__global__ void finalnorm(const float* __restrict__ y, const float2* __restrict__ stats,
                          float* __restrict__ out) {
    size_t i = (size_t)blockIdx.x * 256 + threadIdx.x;
    if (i >= (size_t)B_ * F_ * S_) return;
    float2 st = stats[i / S_];
    float v = fmaxf(y[i], 0.f);
    out[i] = (v - st.x) * st.y;
}

// ---------------------------------------------------------------------------
extern "C" void kernel_launch(void* const* d_in, const int* in_sizes, int n_in,
                              void* d_out, int out_size, void* d_ws, size_t ws_size,
                              hipStream_t stream) {
    const float* inp = (const float*)d_in[0];
    const float* pos = (const float*)d_in[1];
    const float* divisor = (const float*)d_in[2];
    const float* w[6] = { (const float*)d_in[3], (const float*)d_in[4],
                          (const float*)d_in[5], (const float*)d_in[6],
                          (const float*)d_in[7], (const float*)d_in[8] };
    float* out = (float*)d_out;

    size_t off = 0;
    auto alloc = [&](size_t bytes) {
        off = (off + 255) & ~(size_t)255;
        void* r = (char*)d_ws + off;
        off += bytes;
        return r;
    };

    const size_t needB = ((BSPF_ * 2 + 255) & ~255UL)
                       + ((3 * BSPF_ * 2 + 255) & ~255UL)
                       + ((3 * 7 * FF_ * 2 + 255) & ~255UL)
                       + ((3 * BFS_ * 2 + 255) & ~255UL)
                       + ((3 * BFS_ * 2 + 255) & ~255UL)
                       + ((3 * B_ * F_ * 8 + 255) & ~255UL)
                       + ((B_ * NC_ * S_ * 4 + 255) & ~255UL)
                       + 4096;

    if (ws_size >= needB) {
        // NOTE: allocation ORDER matters — conv_gemm8's B staging overreads up
        // to 58 rows past a slab end (never consumed); xT overflow lands in
        // hT3, hT3 overflow lands in Wb3. Keep xT -> hT3 -> Wb3 adjacency.
        bf16* xT   = (bf16*)alloc(BSPF_ * 2);
        bf16* hT3  = (bf16*)alloc(3 * BSPF_ * 2);
        bf16* Wb3  = (bf16*)alloc(3 * 7 * FF_ * 2);
        bf16* O3   = (bf16*)alloc(3 * BFS_ * 2);
        bf16* br3  = (bf16*)alloc(3 * BFS_ * 2);
        float2* stats3 = (float2*)alloc(3 * B_ * F_ * 8);
        float* partials = (float*)alloc(B_ * NC_ * S_ * 4);
        float* ybuf = (float*)O3;   // O3 dead after normT

        zero_pads<<<(4 * B_ * (K_ - 1) * F_ + 255) / 256, 256, 0, stream>>>(xT, hT3, 3);
        prep_x<<<dim3(S_ / 64, F_ / 64, B_), 256, 0, stream>>>(inp, pos, xT);

        for (int j = 0; j < 3; ++j)
            wconv<<<F_ * F_ / 256, 256, 0, stream>>>(w[2 * j], Wb3 + j * 7 * FF_);
        conv_gemm8<<<384, 512, 0, stream>>>(Wb3, xT, O3, 7 * FF_, 0, BFS_);
        rowstats_bf16<<<3 * B_ * F_ / 4, 256, 0, stream>>>(O3, stats3);
        normT<<<dim3(S_ / 64, F_ / 64, 12), 256, 0, stream>>>(O3, stats3, hT3);

        for (int j = 0; j < 3; ++j)
            wconv<<<F_ * F_ / 256, 256, 0, stream>>>(w[2 * j + 1], Wb3 + j * 7 * FF_);
        conv_gemm8<<<384, 512, 0, stream>>>(Wb3, hT3, br3, 7 * FF_, BSPF_, BFS_);

        combine_partial<<<B_ * NC_ * S_ / 256, 256, 0, stream>>>(br3, partials);
        combine_apply<<<B_ * NC_ * S_ / 256, 256, 0, stream>>>(
            inp, divisor, br3, br3 + BFS_, br3 + 2 * BFS_, partials, ybuf);
        rowstats_f32<<<B_ * F_ / 4, 256, 0, stream>>>(ybuf, stats3);
        finalnorm<<<(B_ * F_ * S_) / 256, 256, 0, stream>>>(ybuf, stats3, out);
    } else {
        // sequential fallback (compact ws), proven path
        bf16* xT   = (bf16*)alloc(BSPF_ * 2);
        bf16* hT1  = (bf16*)alloc(BSPF_ * 2);
        bf16* Wb1  = (bf16*)alloc(7 * FF_ * 2);
        bf16* O1   = (bf16*)alloc(BFS_ * 2);
        bf16* br3  = (bf16*)alloc(3 * BFS_ * 2);
        float2* stats3 = (float2*)alloc(B_ * F_ * 8);
        float* partials = (float*)alloc(B_ * NC_ * S_ * 4);
        float* ybuf = (float*)xT;

        zero_pads<<<(2 * B_ * (K_ - 1) * F_ + 255) / 256, 256, 0, stream>>>(xT, hT1, 1);
        prep_x<<<dim3(S_ / 64, F_ / 64, B_), 256, 0, stream>>>(inp, pos, xT);

        for (int j = 0; j < 3; ++j) {
            wconv<<<F_ * F_ / 256, 256, 0, stream>>>(w[2 * j], Wb1);
            conv_gemm_small<<<16 * 8 * 4, 256, 0, stream>>>(Wb1, xT, O1);
            rowstats_bf16<<<B_ * F_ / 4, 256, 0, stream>>>(O1, stats3);
            normT<<<dim3(S_ / 64, F_ / 64, 4), 256, 0, stream>>>(O1, stats3, hT1);
            wconv<<<F_ * F_ / 256, 256, 0, stream>>>(w[2 * j + 1], Wb1);
            conv_gemm_small<<<16 * 8 * 4, 256, 0, stream>>>(Wb1, hT1, br3 + j * BFS_);
        }
        combine_partial<<<B_ * NC_ * S_ / 256, 256, 0, stream>>>(br3, partials);
        combine_apply<<<B_ * NC_ * S_ / 256, 256, 0, stream>>>(
            inp, divisor, br3, br3 + BFS_, br3 + 2 * BFS_, partials, ybuf);
        rowstats_f32<<<B_ * F_ / 4, 256, 0, stream>>>(ybuf, stats3);
        finalnorm<<<(B_ * F_ * S_) / 256, 256, 0, stream>>>(ybuf, stats3, out);
    }
}